// Round 1
// baseline (540.705 us; speedup 1.0000x reference)
//
#include <hip/hip_runtime.h>
#include <hip/hip_fp16.h>

#define DM   1024
#define NH   16
#define HD   64
#define BATCH 4
#define SEQ  2048
#define MROWS (BATCH*SEQ)            // 8192
#define BHSD  ((size_t)BATCH*NH*SEQ*HD)  // 8388608 elems

using f32x4 = __attribute__((ext_vector_type(4))) float;
using f16x8 = __attribute__((ext_vector_type(8))) _Float16;
using s16x8 = __attribute__((ext_vector_type(8))) short;

__device__ __forceinline__ void gload_lds16(const void* g, void* l) {
    __builtin_amdgcn_global_load_lds(
        (const __attribute__((address_space(1))) void*)g,
        (__attribute__((address_space(3))) void*)l, 16, 0, 0);
}

// ---------------- fp32 -> fp16 cast ----------------
__global__ __launch_bounds__(256) void f32_to_f16(const float* __restrict__ in,
                                                  _Float16* __restrict__ out, int n) {
    int i = (blockIdx.x * 256 + threadIdx.x) * 4;
    if (i >= n) return;
    float4 v = *(const float4*)(in + i);
    union { _Float16 h[4]; ushort4 u; } cv;
    cv.h[0] = (_Float16)v.x; cv.h[1] = (_Float16)v.y;
    cv.h[2] = (_Float16)v.z; cv.h[3] = (_Float16)v.w;
    *(ushort4*)(out + i) = cv.u;
}

// ---------------- RoPE cos/sin table: [SEQ][32] float2 ----------------
__global__ __launch_bounds__(256) void rope_table(const int* __restrict__ pos,
                                                  float2* __restrict__ tab) {
    int idx = blockIdx.x * 256 + threadIdx.x;    // 65536
    int s = idx >> 5, j = idx & 31;
    float p = (float)pos[s];
    float invf = powf(10000.0f, -(float)j / 32.0f);
    float ang = p * invf;
    tab[idx] = make_float2(cosf(ang), sinf(ang));
}

// ---------------- GEMM: C = A(MxK) * W^T, W row-major (N x K) ----------------
// MODE 0: write fp32 to outF (row-major MxN)
// MODE 1: fused RoPE epilogue -> qkv fp16 in [3][B][H][S][D]; N=3072
template<int MODE>
__global__ __launch_bounds__(256)
void gemm_f16(const _Float16* __restrict__ A, const _Float16* __restrict__ Bw,
              float* __restrict__ outF, _Float16* __restrict__ qkv,
              const float2* __restrict__ rope) {
    __shared__ __align__(16) _Float16 lds[2][2][128][32];   // [dbuf][A/B][row][k] = 32 KiB
    const int tid  = threadIdx.x;
    const int lane = tid & 63;
    const int wid  = tid >> 6;
    const int m0 = blockIdx.x * 128;
    const int n0 = blockIdx.y * 128;
    const int wm = (wid >> 1) * 64;
    const int wn = (wid & 1) * 64;
    const int g   = lane >> 4;
    const int r16 = lane & 15;

    // staging: 1 KiB chunk c covers rows 16c..16c+15 (64B rows, 4x16B chunks/row).
    // logical k-chunk stored at phys chunk (chunk ^ ((row>>1)&3)) via pre-swizzled src.
    const int srow0 = (wid*2 + 0)*16 + (lane >> 2);
    const int srow1 = (wid*2 + 1)*16 + (lane >> 2);
    const int sch0 = (lane & 3) ^ ((srow0 >> 1) & 3);
    const int sch1 = (lane & 3) ^ ((srow1 >> 1) & 3);
    const _Float16* Asrc0 = A  + (size_t)(m0 + srow0)*DM + sch0*8;
    const _Float16* Asrc1 = A  + (size_t)(m0 + srow1)*DM + sch1*8;
    const _Float16* Bsrc0 = Bw + (size_t)(n0 + srow0)*DM + sch0*8;
    const _Float16* Bsrc1 = Bw + (size_t)(n0 + srow1)*DM + sch1*8;

    f32x4 acc[4][4] = {};

    #define STAGE(buf, kt) do {                                           \
        const int koff = (kt)*32;                                         \
        _Float16* bA = &lds[(buf)][0][0][0];                              \
        _Float16* bB = &lds[(buf)][1][0][0];                              \
        gload_lds16(Asrc0 + koff, bA + (wid*2 + 0)*512);                  \
        gload_lds16(Asrc1 + koff, bA + (wid*2 + 1)*512);                  \
        gload_lds16(Bsrc0 + koff, bB + (wid*2 + 0)*512);                  \
        gload_lds16(Bsrc1 + koff, bB + (wid*2 + 1)*512);                  \
    } while (0)

    STAGE(0, 0);
    for (int kt = 0; kt < 32; ++kt) {
        __syncthreads();                 // drains vmcnt(0): buf[kt&1] ready
        if (kt + 1 < 32) STAGE((kt + 1) & 1, kt + 1);
        const int buf = kt & 1;
        f16x8 af[4], bf[4];
        #pragma unroll
        for (int i = 0; i < 4; ++i) {
            int rowa = wm + i*16 + r16;
            af[i] = *(const f16x8*)&lds[buf][0][rowa][(g ^ ((rowa >> 1) & 3)) * 8];
            int rowb = wn + i*16 + r16;
            bf[i] = *(const f16x8*)&lds[buf][1][rowb][(g ^ ((rowb >> 1) & 3)) * 8];
        }
        #pragma unroll
        for (int i = 0; i < 4; ++i)
            #pragma unroll
            for (int j = 0; j < 4; ++j)
                acc[i][j] = __builtin_amdgcn_mfma_f32_16x16x32_f16(af[i], bf[j], acc[i][j], 0, 0, 0);
    }
    #undef STAGE

    // epilogue
    #pragma unroll
    for (int i = 0; i < 4; ++i) {
        #pragma unroll
        for (int j = 0; j < 4; ++j) {
            #pragma unroll
            for (int r = 0; r < 4; ++r) {
                const int m = m0 + wm + i*16 + g*4 + r;   // C row = (lane>>4)*4 + reg
                const int n = n0 + wn + j*16 + r16;       // C col = lane&15
                float v = acc[i][j][r];
                if constexpr (MODE == 0) {
                    outF[(size_t)m*DM + n] = v;
                } else {
                    float vp = __shfl_xor(v, 1);          // partner column (n^1)
                    const int sel = n >> 10;              // 0=q 1=k 2=v (block-uniform)
                    const int cc = n & 1023;
                    const int h = cc >> 6, dd = cc & 63;
                    const int s = m & (SEQ - 1), b = m >> 11;
                    float o;
                    if (sel < 2) {
                        float2 cs = rope[(s << 5) + (dd >> 1)];
                        if (dd & 1) o = vp * cs.y + v * cs.x;   // x1*sin + x2*cos
                        else        o = v * cs.x - vp * cs.y;   // x1*cos - x2*sin
                        if (sel == 0) o *= 0.125f;              // fold 1/sqrt(HD) into Q
                    } else {
                        o = v;
                    }
                    qkv[(size_t)sel*BHSD + ((size_t)((b*NH + h)*SEQ + s))*HD + dd] = (_Float16)o;
                }
            }
        }
    }
}

// ---------------- flash attention: causal, fp16 in/out, fp32 softmax ----------------
__global__ __launch_bounds__(256)
void attn_kernel(const _Float16* __restrict__ qkv, _Float16* __restrict__ ao) {
    const int tid = threadIdx.x, lane = tid & 63, w = tid >> 6;
    const int g = lane >> 4, r16 = lane & 15;
    const int bh = blockIdx.y;
    const int q0 = ((int)gridDim.x - 1 - (int)blockIdx.x) * 64;  // big-work blocks first
    const _Float16* Q  = qkv + (size_t)bh * SEQ * HD;
    const _Float16* Kp = qkv + BHSD + (size_t)bh * SEQ * HD;
    const _Float16* Vp = qkv + 2*BHSD + (size_t)bh * SEQ * HD;

    __shared__ __align__(16) _Float16 Kl[32][64];     // XOR-swizzled 16B chunks
    __shared__ __align__(16) _Float16 Vt[64][40];     // V^T, padded stride 80B
    __shared__ __align__(16) _Float16 Pl[4][16][40];  // per-wave P, padded

    const int qrow = q0 + w*16 + r16;
    f16x8 qf[2];
    qf[0] = *(const f16x8*)(Q + (size_t)qrow*HD + g*8);
    qf[1] = *(const f16x8*)(Q + (size_t)qrow*HD + 32 + g*8);

    f32x4 of[4] = {};
    float mr[4], lr[4];
    #pragma unroll
    for (int r = 0; r < 4; ++r) { mr[r] = -INFINITY; lr[r] = 0.f; }

    const int myqmax = q0 + w*16 + 15;
    const int nt = (q0 + 64) >> 5;

    // K staging (global_load_lds, pre-swizzled source): phys 16B unit p = w*64+lane
    const int sp = w*64 + lane;
    const int skv = sp >> 3;
    const int slc = (sp & 7) ^ (skv & 7);
    const _Float16* Ksrc = Kp + (size_t)skv*HD + slc*8;
    // V staging (transpose into Vt)
    const int vkv = tid >> 3, vd0 = (tid & 7) * 8;
    const _Float16* Vsrc = Vp + (size_t)vkv*HD + vd0;

    for (int kt = 0; kt < nt; ++kt) {
        const int kv0 = kt << 5;
        __syncthreads();                         // prev tile fully consumed
        gload_lds16(Ksrc + (size_t)kv0*HD, (_Float16*)&Kl[0][0] + w*512);
        s16x8 vv = *(const s16x8*)(Vsrc + (size_t)kv0*HD);
        #pragma unroll
        for (int j = 0; j < 8; ++j)
            Vt[vd0 + j][vkv] = ((const _Float16*)&vv)[j];
        __syncthreads();                         // waits vmcnt(0)+lgkmcnt(0)

        if (myqmax < kv0) continue;              // wave has no unmasked work

        // S = Q K^T  (Q pre-scaled by 1/8)
        f32x4 sc[2] = {};
        #pragma unroll
        for (int ks = 0; ks < 2; ++ks) {
            #pragma unroll
            for (int ns = 0; ns < 2; ++ns) {
                int krow = ns*16 + r16;
                f16x8 kf = *(const f16x8*)&Kl[krow][((ks*4 + g) ^ (krow & 7)) * 8];
                sc[ns] = __builtin_amdgcn_mfma_f32_16x16x32_f16(qf[ks], kf, sc[ns], 0, 0, 0);
            }
        }

        // online softmax (C layout: col=lane&15 -> kv, row=(lane>>4)*4+r -> q)
        const int qg = q0 + w*16 + g*4;
        #pragma unroll
        for (int r = 0; r < 4; ++r) {
            const int qr = qg + r;
            float s0 = (kv0 + r16      <= qr) ? sc[0][r] : -INFINITY;
            float s1 = (kv0 + 16 + r16 <= qr) ? sc[1][r] : -INFINITY;
            float tm = fmaxf(s0, s1);
            tm = fmaxf(tm, __shfl_xor(tm, 1));
            tm = fmaxf(tm, __shfl_xor(tm, 2));
            tm = fmaxf(tm, __shfl_xor(tm, 4));
            tm = fmaxf(tm, __shfl_xor(tm, 8));
            float mnew = fmaxf(mr[r], tm);
            float alpha = __expf(mr[r] - mnew);
            float p0 = __expf(s0 - mnew);
            float p1 = __expf(s1 - mnew);
            float ps = p0 + p1;
            ps += __shfl_xor(ps, 1);
            ps += __shfl_xor(ps, 2);
            ps += __shfl_xor(ps, 4);
            ps += __shfl_xor(ps, 8);
            lr[r] = lr[r] * alpha + ps;
            mr[r] = mnew;
            #pragma unroll
            for (int n = 0; n < 4; ++n) of[n][r] *= alpha;
            const int prow = g*4 + r;
            Pl[w][prow][r16]      = (_Float16)p0;
            Pl[w][prow][16 + r16] = (_Float16)p1;
        }

        // O += P V   (P: A-operand from LDS; V^T: B-operand)
        f16x8 pa = *(const f16x8*)&Pl[w][r16][g*8];
        #pragma unroll
        for (int n = 0; n < 4; ++n) {
            f16x8 vf = *(const f16x8*)&Vt[n*16 + r16][g*8];
            of[n] = __builtin_amdgcn_mfma_f32_16x16x32_f16(pa, vf, of[n], 0, 0, 0);
        }
    }

    // normalize + store to ao[B*S][DM] at col h*64+d
    const int b = bh >> 4, h = bh & 15;
    #pragma unroll
    for (int r = 0; r < 4; ++r) {
        float inv = 1.0f / lr[r];
        const int srow = q0 + w*16 + g*4 + r;
        _Float16* dst = ao + ((size_t)(b*SEQ + srow))*DM + h*HD + r16;
        #pragma unroll
        for (int n = 0; n < 4; ++n)
            dst[n*16] = (_Float16)(of[n][r] * inv);
    }
}

// ---------------- launcher ----------------
extern "C" void kernel_launch(void* const* d_in, const int* in_sizes, int n_in,
                              void* d_out, int out_size, void* d_ws, size_t ws_size,
                              hipStream_t stream) {
    const float* x  = (const float*)d_in[0];
    const int*   tp = (const int*)d_in[1];
    const float* wq = (const float*)d_in[2];
    const float* wk = (const float*)d_in[3];
    const float* wv = (const float*)d_in[4];
    const float* wo = (const float*)d_in[5];
    float* out = (float*)d_out;

    char* ws = (char*)d_ws;
    _Float16* xh  = (_Float16*)(ws);                         // 16,777,216 B
    _Float16* whq = (_Float16*)(ws + 16777216);              //  6,291,456 B (wq|wk|wv)
    _Float16* woh = (_Float16*)(ws + 23068672);              //  2,097,152 B
    _Float16* qkv = (_Float16*)(ws + 25165824);              // 50,331,648 B
    _Float16* ao  = (_Float16*)(ws + 75497472);              // 16,777,216 B
    float2*   rope= (float2*)  (ws + 92274688);              //    524,288 B  (total ~92.8 MB)

    f32_to_f16<<<MROWS*DM/1024, 256, 0, stream>>>(x, xh, MROWS*DM);
    f32_to_f16<<<DM*DM/1024, 256, 0, stream>>>(wq, whq,            DM*DM);
    f32_to_f16<<<DM*DM/1024, 256, 0, stream>>>(wk, whq + DM*DM,    DM*DM);
    f32_to_f16<<<DM*DM/1024, 256, 0, stream>>>(wv, whq + 2*DM*DM,  DM*DM);
    f32_to_f16<<<DM*DM/1024, 256, 0, stream>>>(wo, woh,            DM*DM);
    rope_table<<<SEQ*32/256, 256, 0, stream>>>(tp, rope);

    gemm_f16<1><<<dim3(MROWS/128, 3*DM/128), 256, 0, stream>>>(xh, whq, nullptr, qkv, rope);
    attn_kernel<<<dim3(SEQ/64, BATCH*NH), 256, 0, stream>>>(qkv, ao);
    gemm_f16<0><<<dim3(MROWS/128, DM/128), 256, 0, stream>>>(ao, woh, out, nullptr, nullptr);
}

// Round 2
// 362.416 us; speedup vs baseline: 1.4919x; 1.4919x over previous
//
#include <hip/hip_runtime.h>
#include <hip/hip_fp16.h>

#define DM   1024
#define NH   16
#define HD   64
#define BATCH 4
#define SEQ  2048
#define MROWS (BATCH*SEQ)            // 8192
#define BHSD  ((size_t)BATCH*NH*SEQ*HD)  // 8388608 elems

using f32x4 = __attribute__((ext_vector_type(4))) float;
using f16x8 = __attribute__((ext_vector_type(8))) _Float16;
using f16x4 = __attribute__((ext_vector_type(4))) _Float16;

__device__ __forceinline__ void gload_lds16(const void* g, void* l) {
    __builtin_amdgcn_global_load_lds(
        (const __attribute__((address_space(1))) void*)g,
        (__attribute__((address_space(3))) void*)l, 16, 0, 0);
}

// ---------------- fp32 -> fp16 cast ----------------
__global__ __launch_bounds__(256) void f32_to_f16(const float* __restrict__ in,
                                                  _Float16* __restrict__ out, int n) {
    int i = (blockIdx.x * 256 + threadIdx.x) * 4;
    if (i >= n) return;
    float4 v = *(const float4*)(in + i);
    union { _Float16 h[4]; ushort4 u; } cv;
    cv.h[0] = (_Float16)v.x; cv.h[1] = (_Float16)v.y;
    cv.h[2] = (_Float16)v.z; cv.h[3] = (_Float16)v.w;
    *(ushort4*)(out + i) = cv.u;
}

// ---------------- RoPE cos/sin table: [SEQ][32] float2 ----------------
__global__ __launch_bounds__(256) void rope_table(const int* __restrict__ pos,
                                                  float2* __restrict__ tab) {
    int idx = blockIdx.x * 256 + threadIdx.x;    // 65536
    int s = idx >> 5, j = idx & 31;
    float p = (float)pos[s];
    float invf = powf(10000.0f, -(float)j / 32.0f);
    float ang = p * invf;
    tab[idx] = make_float2(cosf(ang), sinf(ang));
}

// ---------------- GEMM: C = A(MxK) * W^T, W row-major (N x K) ----------------
// MODE 0: write fp32 to outF (row-major MxN)
// MODE 1: fused RoPE epilogue -> q,k fp16 in [B][H][S][D]; V TRANSPOSED [B][H][D][S]
template<int MODE>
__global__ __launch_bounds__(256)
void gemm_f16(const _Float16* __restrict__ A, const _Float16* __restrict__ Bw,
              float* __restrict__ outF, _Float16* __restrict__ qkv,
              const float2* __restrict__ rope) {
    __shared__ __align__(16) _Float16 lds[2][2][128][32];   // [dbuf][A/B][row][k] = 32 KiB
    const int tid  = threadIdx.x;
    const int lane = tid & 63;
    const int wid  = tid >> 6;
    const int m0 = blockIdx.x * 128;
    const int n0 = blockIdx.y * 128;
    const int wm = (wid >> 1) * 64;
    const int wn = (wid & 1) * 64;
    const int g   = lane >> 4;
    const int r16 = lane & 15;

    const int srow0 = (wid*2 + 0)*16 + (lane >> 2);
    const int srow1 = (wid*2 + 1)*16 + (lane >> 2);
    const int sch0 = (lane & 3) ^ ((srow0 >> 1) & 3);
    const int sch1 = (lane & 3) ^ ((srow1 >> 1) & 3);
    const _Float16* Asrc0 = A  + (size_t)(m0 + srow0)*DM + sch0*8;
    const _Float16* Asrc1 = A  + (size_t)(m0 + srow1)*DM + sch1*8;
    const _Float16* Bsrc0 = Bw + (size_t)(n0 + srow0)*DM + sch0*8;
    const _Float16* Bsrc1 = Bw + (size_t)(n0 + srow1)*DM + sch1*8;

    f32x4 acc[4][4] = {};

    #define STAGE(buf, kt) do {                                           \
        const int koff = (kt)*32;                                         \
        _Float16* bA = &lds[(buf)][0][0][0];                              \
        _Float16* bB = &lds[(buf)][1][0][0];                              \
        gload_lds16(Asrc0 + koff, bA + (wid*2 + 0)*512);                  \
        gload_lds16(Asrc1 + koff, bA + (wid*2 + 1)*512);                  \
        gload_lds16(Bsrc0 + koff, bB + (wid*2 + 0)*512);                  \
        gload_lds16(Bsrc1 + koff, bB + (wid*2 + 1)*512);                  \
    } while (0)

    STAGE(0, 0);
    for (int kt = 0; kt < 32; ++kt) {
        __syncthreads();
        if (kt + 1 < 32) STAGE((kt + 1) & 1, kt + 1);
        const int buf = kt & 1;
        f16x8 af[4], bf[4];
        #pragma unroll
        for (int i = 0; i < 4; ++i) {
            int rowa = wm + i*16 + r16;
            af[i] = *(const f16x8*)&lds[buf][0][rowa][(g ^ ((rowa >> 1) & 3)) * 8];
            int rowb = wn + i*16 + r16;
            bf[i] = *(const f16x8*)&lds[buf][1][rowb][(g ^ ((rowb >> 1) & 3)) * 8];
        }
        #pragma unroll
        for (int i = 0; i < 4; ++i)
            #pragma unroll
            for (int j = 0; j < 4; ++j)
                acc[i][j] = __builtin_amdgcn_mfma_f32_16x16x32_f16(af[i], bf[j], acc[i][j], 0, 0, 0);
    }
    #undef STAGE

    // epilogue
    #pragma unroll
    for (int i = 0; i < 4; ++i) {
        #pragma unroll
        for (int j = 0; j < 4; ++j) {
            if constexpr (MODE == 0) {
                #pragma unroll
                for (int r = 0; r < 4; ++r) {
                    const int m = m0 + wm + i*16 + g*4 + r;
                    const int n = n0 + wn + j*16 + r16;
                    outF[(size_t)m*DM + n] = acc[i][j][r];
                }
            } else {
                const int n = n0 + wn + j*16 + r16;
                const int sel = n >> 10;              // 0=q 1=k 2=v (block-uniform)
                const int cc = n & 1023;
                const int h = cc >> 6, dd = cc & 63;
                if (sel == 2) {
                    // V^T: 4 consecutive s (r=0..3) at fixed d -> one 8B store
                    const int mb = m0 + wm + i*16 + g*4;
                    const int s0 = mb & (SEQ - 1), b = mb >> 11;
                    f16x4 pk;
                    #pragma unroll
                    for (int r = 0; r < 4; ++r) pk[r] = (_Float16)acc[i][j][r];
                    *(f16x4*)(qkv + 2*BHSD + ((size_t)((b*NH + h)*HD + dd))*SEQ + s0) = pk;
                } else {
                    #pragma unroll
                    for (int r = 0; r < 4; ++r) {
                        const int m = m0 + wm + i*16 + g*4 + r;
                        float v = acc[i][j][r];
                        float vp = __shfl_xor(v, 1);          // partner column (n^1)
                        const int s = m & (SEQ - 1), b = m >> 11;
                        float2 cs = rope[(s << 5) + (dd >> 1)];
                        float o;
                        if (dd & 1) o = vp * cs.y + v * cs.x;   // x1*sin + x2*cos
                        else        o = v * cs.x - vp * cs.y;   // x1*cos - x2*sin
                        if (sel == 0) o *= 0.125f;              // fold 1/sqrt(HD) into Q
                        qkv[(size_t)sel*BHSD + ((size_t)((b*NH + h)*SEQ + s))*HD + dd] = (_Float16)o;
                    }
                }
            }
        }
    }
}

// ---------------- flash attention: causal, Q-tile 128, KV-tile 64, 4 waves ----------------
__global__ __launch_bounds__(256)
void attn_kernel(const _Float16* __restrict__ qkv, _Float16* __restrict__ ao) {
    const int tid = threadIdx.x, lane = tid & 63, w = tid >> 6;
    const int g = lane >> 4, r16 = lane & 15;
    const int bh = blockIdx.y;
    const int q0 = (15 - (int)blockIdx.x) * 128;          // big-work blocks first
    const _Float16* Q   = qkv + (size_t)bh * SEQ * HD;
    const _Float16* Kp  = qkv + BHSD + (size_t)bh * SEQ * HD;
    const _Float16* Vpt = qkv + 2*BHSD + (size_t)bh * SEQ * HD;   // [d][s]

    __shared__ __align__(16) _Float16 Kl[2][64][64];   // 16 KB, XOR-swizzled chunks
    __shared__ __align__(16) _Float16 Vl[2][64][64];   // 16 KB, V^T rows=d
    __shared__ __align__(16) _Float16 Pl[4][32][72];   // 18 KB, per-wave P

    // staging addresses (unit u = shot*256 + tid; row = u>>3, phys chunk = u&7)
    const int rA = tid >> 3,        rB = 32 + (tid >> 3);
    const int lcA = (tid & 7) ^ (rA & 7), lcB = (tid & 7) ^ (rB & 7);
    const _Float16* KsrcA = Kp  + (size_t)rA*HD + lcA*8;
    const _Float16* KsrcB = Kp  + (size_t)rB*HD + lcB*8;
    const _Float16* VsrcA = Vpt + (size_t)rA*SEQ + lcA*8;
    const _Float16* VsrcB = Vpt + (size_t)rB*SEQ + lcB*8;

    // Q fragments: 32 rows/wave, held in registers (pre-scaled by 1/8 in GEMM epilogue)
    const int R = q0 + w*32;
    f16x8 qfr[2][2];
    #pragma unroll
    for (int qi = 0; qi < 2; ++qi)
        #pragma unroll
        for (int ks = 0; ks < 2; ++ks)
            qfr[qi][ks] = *(const f16x8*)(Q + (size_t)(R + qi*16 + r16)*HD + ks*32 + g*8);

    f32x4 of[2][4] = {};
    float mr[2][4], lr[2][4];
    #pragma unroll
    for (int qi = 0; qi < 2; ++qi)
        #pragma unroll
        for (int r = 0; r < 4; ++r) { mr[qi][r] = -INFINITY; lr[qi][r] = 0.f; }

    const int nt = (q0 >> 6) + 2;

    #define STAGE(buf, kv0) do {                                              \
        gload_lds16(KsrcA + (size_t)(kv0)*HD, &Kl[(buf)][0][0] + tid*8);      \
        gload_lds16(KsrcB + (size_t)(kv0)*HD, &Kl[(buf)][0][0] + (256+tid)*8);\
        gload_lds16(VsrcA + (kv0),            &Vl[(buf)][0][0] + tid*8);      \
        gload_lds16(VsrcB + (kv0),            &Vl[(buf)][0][0] + (256+tid)*8);\
    } while (0)

    STAGE(0, 0);
    for (int kt = 0; kt < nt; ++kt) {
        const int kv0 = kt << 6;
        __syncthreads();                         // buf[kt&1] ready; buf[kt+1&1] free
        if (kt + 1 < nt) STAGE((kt + 1) & 1, (kt + 1) << 6);
        const int buf = kt & 1;

        if (kv0 <= R + 31) {                     // wave has unmasked work
            // ---- S = Q K^T ----
            f32x4 sc[2][4] = {};
            __builtin_amdgcn_s_setprio(1);
            #pragma unroll
            for (int ks = 0; ks < 2; ++ks) {
                f16x8 kf[4];
                #pragma unroll
                for (int n = 0; n < 4; ++n) {
                    int krow = n*16 + r16;
                    kf[n] = *(const f16x8*)&Kl[buf][krow][(((ks<<2)|g) ^ (krow & 7))*8];
                }
                #pragma unroll
                for (int qi = 0; qi < 2; ++qi)
                    #pragma unroll
                    for (int n = 0; n < 4; ++n)
                        sc[qi][n] = __builtin_amdgcn_mfma_f32_16x16x32_f16(qfr[qi][ks], kf[n], sc[qi][n], 0, 0, 0);
            }
            __builtin_amdgcn_s_setprio(0);

            // ---- online softmax ----
            const bool fullTile = (kv0 + 63 <= R);
            #pragma unroll
            for (int qi = 0; qi < 2; ++qi) {
                #pragma unroll
                for (int r = 0; r < 4; ++r) {
                    const int qr = R + qi*16 + g*4 + r;
                    float sv[4];
                    #pragma unroll
                    for (int n = 0; n < 4; ++n) {
                        float s = sc[qi][n][r];
                        sv[n] = (fullTile || (kv0 + n*16 + r16 <= qr)) ? s : -INFINITY;
                    }
                    float mx = fmaxf(fmaxf(sv[0], sv[1]), fmaxf(sv[2], sv[3]));
                    mx = fmaxf(mx, __shfl_xor(mx, 1));
                    mx = fmaxf(mx, __shfl_xor(mx, 2));
                    mx = fmaxf(mx, __shfl_xor(mx, 4));
                    mx = fmaxf(mx, __shfl_xor(mx, 8));
                    float mnew = fmaxf(mr[qi][r], mx);
                    float al = __expf(mr[qi][r] - mnew);
                    float ps = 0.f;
                    #pragma unroll
                    for (int n = 0; n < 4; ++n) { sv[n] = __expf(sv[n] - mnew); ps += sv[n]; }
                    ps += __shfl_xor(ps, 1);
                    ps += __shfl_xor(ps, 2);
                    ps += __shfl_xor(ps, 4);
                    ps += __shfl_xor(ps, 8);
                    lr[qi][r] = lr[qi][r] * al + ps;
                    mr[qi][r] = mnew;
                    #pragma unroll
                    for (int n = 0; n < 4; ++n) of[qi][n][r] *= al;
                    const int prow = qi*16 + g*4 + r;
                    #pragma unroll
                    for (int n = 0; n < 4; ++n)
                        Pl[w][prow][n*16 + r16] = (_Float16)sv[n];
                }
            }

            // ---- O += P V ----
            __builtin_amdgcn_s_setprio(1);
            #pragma unroll
            for (int qi = 0; qi < 2; ++qi) {
                #pragma unroll
                for (int ks = 0; ks < 2; ++ks) {
                    f16x8 pa = *(const f16x8*)&Pl[w][qi*16 + r16][(ks*4 + g)*8];
                    #pragma unroll
                    for (int n = 0; n < 4; ++n) {
                        int vrow = n*16 + r16;
                        f16x8 vf = *(const f16x8*)&Vl[buf][vrow][(((ks<<2)|g) ^ (vrow & 7))*8];
                        of[qi][n] = __builtin_amdgcn_mfma_f32_16x16x32_f16(pa, vf, of[qi][n], 0, 0, 0);
                    }
                }
            }
            __builtin_amdgcn_s_setprio(0);
        }
    }
    #undef STAGE

    // normalize + store to ao[B*S][DM] at col h*64 + d
    const int b = bh >> 4, h = bh & 15;
    #pragma unroll
    for (int qi = 0; qi < 2; ++qi) {
        #pragma unroll
        for (int r = 0; r < 4; ++r) {
            float inv = 1.0f / lr[qi][r];
            const int srow = R + qi*16 + g*4 + r;
            _Float16* dst = ao + ((size_t)(b*SEQ + srow))*DM + h*HD + r16;
            #pragma unroll
            for (int n = 0; n < 4; ++n)
                dst[n*16] = (_Float16)(of[qi][n][r] * inv);
        }
    }
}

// ---------------- launcher ----------------
extern "C" void kernel_launch(void* const* d_in, const int* in_sizes, int n_in,
                              void* d_out, int out_size, void* d_ws, size_t ws_size,
                              hipStream_t stream) {
    const float* x  = (const float*)d_in[0];
    const int*   tp = (const int*)d_in[1];
    const float* wq = (const float*)d_in[2];
    const float* wk = (const float*)d_in[3];
    const float* wv = (const float*)d_in[4];
    const float* wo = (const float*)d_in[5];
    float* out = (float*)d_out;

    char* ws = (char*)d_ws;
    _Float16* xh  = (_Float16*)(ws);                         // 16,777,216 B
    _Float16* whq = (_Float16*)(ws + 16777216);              //  6,291,456 B (wq|wk|wv)
    _Float16* woh = (_Float16*)(ws + 23068672);              //  2,097,152 B
    _Float16* qkv = (_Float16*)(ws + 25165824);              // 50,331,648 B
    _Float16* ao  = (_Float16*)(ws + 75497472);              // 16,777,216 B
    float2*   rope= (float2*)  (ws + 92274688);              //    524,288 B  (total ~92.8 MB)

    f32_to_f16<<<MROWS*DM/1024, 256, 0, stream>>>(x, xh, MROWS*DM);
    f32_to_f16<<<DM*DM/1024, 256, 0, stream>>>(wq, whq,            DM*DM);
    f32_to_f16<<<DM*DM/1024, 256, 0, stream>>>(wk, whq + DM*DM,    DM*DM);
    f32_to_f16<<<DM*DM/1024, 256, 0, stream>>>(wv, whq + 2*DM*DM,  DM*DM);
    f32_to_f16<<<DM*DM/1024, 256, 0, stream>>>(wo, woh,            DM*DM);
    rope_table<<<SEQ*32/256, 256, 0, stream>>>(tp, rope);

    gemm_f16<1><<<dim3(MROWS/128, 3*DM/128), 256, 0, stream>>>(xh, whq, nullptr, qkv, rope);
    attn_kernel<<<dim3(SEQ/128, BATCH*NH), 256, 0, stream>>>(qkv, ao);
    gemm_f16<0><<<dim3(MROWS/128, DM/128), 256, 0, stream>>>(ao, woh, out, nullptr, nullptr);
}

// Round 4
// 303.353 us; speedup vs baseline: 1.7824x; 1.1947x over previous
//
#include <hip/hip_runtime.h>
#include <hip/hip_fp16.h>

#define DM   1024
#define NH   16
#define HD   64
#define BATCH 4
#define SEQ  2048
#define MROWS (BATCH*SEQ)            // 8192
#define BHSD  ((size_t)BATCH*NH*SEQ*HD)  // 8388608 elems

using f32x4 = __attribute__((ext_vector_type(4))) float;
using f16x8 = __attribute__((ext_vector_type(8))) _Float16;
using f16x4 = __attribute__((ext_vector_type(4))) _Float16;
using fp16x2 = __attribute__((ext_vector_type(2))) __fp16;

__device__ __forceinline__ void gload_lds16(const void* g, void* l) {
    __builtin_amdgcn_global_load_lds(
        (const __attribute__((address_space(1))) void*)g,
        (__attribute__((address_space(3))) void*)l, 16, 0, 0);
}

// ---------------- fp32 -> fp16 cast ----------------
__global__ __launch_bounds__(256) void f32_to_f16(const float* __restrict__ in,
                                                  _Float16* __restrict__ out, int n) {
    int i = (blockIdx.x * 256 + threadIdx.x) * 4;
    if (i >= n) return;
    float4 v = *(const float4*)(in + i);
    union { _Float16 h[4]; ushort4 u; } cv;
    cv.h[0] = (_Float16)v.x; cv.h[1] = (_Float16)v.y;
    cv.h[2] = (_Float16)v.z; cv.h[3] = (_Float16)v.w;
    *(ushort4*)(out + i) = cv.u;
}

// ---------------- RoPE cos/sin table: [SEQ][32] float2 ----------------
__global__ __launch_bounds__(256) void rope_table(const int* __restrict__ pos,
                                                  float2* __restrict__ tab) {
    int idx = blockIdx.x * 256 + threadIdx.x;    // 65536
    int s = idx >> 5, j = idx & 31;
    float p = (float)pos[s];
    float invf = powf(10000.0f, -(float)j / 32.0f);
    float ang = p * invf;
    tab[idx] = make_float2(cosf(ang), sinf(ang));
}

// ---------------- GEMM: C = A(MxK) * W^T, W row-major (N x K) ----------------
// MODE 0: write fp32 to outF (row-major MxN)
// MODE 1: fused RoPE epilogue -> q,k fp16 in [B][H][S][D]; V TRANSPOSED [B][H][D][S]
template<int MODE>
__global__ __launch_bounds__(256)
void gemm_f16(const _Float16* __restrict__ A, const _Float16* __restrict__ Bw,
              float* __restrict__ outF, _Float16* __restrict__ qkv,
              const float2* __restrict__ rope) {
    __shared__ __align__(16) _Float16 lds[2][2][128][32];   // [dbuf][A/B][row][k] = 32 KiB
    const int tid  = threadIdx.x;
    const int lane = tid & 63;
    const int wid  = tid >> 6;
    const int m0 = blockIdx.x * 128;
    const int n0 = blockIdx.y * 128;
    const int wm = (wid >> 1) * 64;
    const int wn = (wid & 1) * 64;
    const int g   = lane >> 4;
    const int r16 = lane & 15;

    const int srow0 = (wid*2 + 0)*16 + (lane >> 2);
    const int srow1 = (wid*2 + 1)*16 + (lane >> 2);
    const int sch0 = (lane & 3) ^ ((srow0 >> 1) & 3);
    const int sch1 = (lane & 3) ^ ((srow1 >> 1) & 3);
    const _Float16* Asrc0 = A  + (size_t)(m0 + srow0)*DM + sch0*8;
    const _Float16* Asrc1 = A  + (size_t)(m0 + srow1)*DM + sch1*8;
    const _Float16* Bsrc0 = Bw + (size_t)(n0 + srow0)*DM + sch0*8;
    const _Float16* Bsrc1 = Bw + (size_t)(n0 + srow1)*DM + sch1*8;

    f32x4 acc[4][4] = {};

    #define STAGE(buf, kt) do {                                           \
        const int koff = (kt)*32;                                         \
        _Float16* bA = &lds[(buf)][0][0][0];                              \
        _Float16* bB = &lds[(buf)][1][0][0];                              \
        gload_lds16(Asrc0 + koff, bA + (wid*2 + 0)*512);                  \
        gload_lds16(Asrc1 + koff, bA + (wid*2 + 1)*512);                  \
        gload_lds16(Bsrc0 + koff, bB + (wid*2 + 0)*512);                  \
        gload_lds16(Bsrc1 + koff, bB + (wid*2 + 1)*512);                  \
    } while (0)

    STAGE(0, 0);
    for (int kt = 0; kt < 32; ++kt) {
        __syncthreads();
        if (kt + 1 < 32) STAGE((kt + 1) & 1, kt + 1);
        const int buf = kt & 1;
        f16x8 af[4], bf[4];
        #pragma unroll
        for (int i = 0; i < 4; ++i) {
            int rowa = wm + i*16 + r16;
            af[i] = *(const f16x8*)&lds[buf][0][rowa][(g ^ ((rowa >> 1) & 3)) * 8];
            int rowb = wn + i*16 + r16;
            bf[i] = *(const f16x8*)&lds[buf][1][rowb][(g ^ ((rowb >> 1) & 3)) * 8];
        }
        #pragma unroll
        for (int i = 0; i < 4; ++i)
            #pragma unroll
            for (int j = 0; j < 4; ++j)
                acc[i][j] = __builtin_amdgcn_mfma_f32_16x16x32_f16(af[i], bf[j], acc[i][j], 0, 0, 0);
    }
    #undef STAGE

    // epilogue
    #pragma unroll
    for (int i = 0; i < 4; ++i) {
        #pragma unroll
        for (int j = 0; j < 4; ++j) {
            if constexpr (MODE == 0) {
                #pragma unroll
                for (int r = 0; r < 4; ++r) {
                    const int m = m0 + wm + i*16 + g*4 + r;
                    const int n = n0 + wn + j*16 + r16;
                    outF[(size_t)m*DM + n] = acc[i][j][r];
                }
            } else {
                const int n = n0 + wn + j*16 + r16;
                const int sel = n >> 10;              // 0=q 1=k 2=v (block-uniform)
                const int cc = n & 1023;
                const int h = cc >> 6, dd = cc & 63;
                if (sel == 2) {
                    // V^T: 4 consecutive s (r=0..3) at fixed d -> one 8B store
                    const int mb = m0 + wm + i*16 + g*4;
                    const int s0 = mb & (SEQ - 1), b = mb >> 11;
                    f16x4 pk;
                    #pragma unroll
                    for (int r = 0; r < 4; ++r) pk[r] = (_Float16)acc[i][j][r];
                    *(f16x4*)(qkv + 2*BHSD + ((size_t)((b*NH + h)*HD + dd))*SEQ + s0) = pk;
                } else {
                    #pragma unroll
                    for (int r = 0; r < 4; ++r) {
                        const int m = m0 + wm + i*16 + g*4 + r;
                        float v = acc[i][j][r];
                        float vp = __shfl_xor(v, 1);          // partner column (n^1)
                        const int s = m & (SEQ - 1), b = m >> 11;
                        float2 cs = rope[(s << 5) + (dd >> 1)];
                        float o;
                        if (dd & 1) o = vp * cs.y + v * cs.x;   // x1*sin + x2*cos
                        else        o = v * cs.x - vp * cs.y;   // x1*cos - x2*sin
                        if (sel == 0) o *= 0.125f;              // fold 1/sqrt(HD) into Q
                        qkv[(size_t)sel*BHSD + ((size_t)((b*NH + h)*SEQ + s))*HD + dd] = (_Float16)o;
                    }
                }
            }
        }
    }
}

// ---------------- flash attention: swapped-QK^T, in-register softmax ----------------
// Q-tile 128/block (32/wave), KV-tile 64, 4 waves. S^T = mfma(K,Q): q = lane&15.
__global__ __launch_bounds__(256)
void attn_kernel(const _Float16* __restrict__ qkv, _Float16* __restrict__ ao) {
    const int tid = threadIdx.x, lane = tid & 63, w = tid >> 6;
    const int g = lane >> 4, r16 = lane & 15;
    const int bh = blockIdx.y;
    const int q0 = (15 - (int)blockIdx.x) * 128;          // big-work blocks first
    const _Float16* Q   = qkv + (size_t)bh * SEQ * HD;
    const _Float16* Kp  = qkv + BHSD + (size_t)bh * SEQ * HD;
    const _Float16* Vpt = qkv + 2*BHSD + (size_t)bh * SEQ * HD;   // [d][s]

    __shared__ __align__(16) _Float16 Kl[2][64][64];   // 16 KB, XOR-swizzled chunks
    __shared__ __align__(16) _Float16 Vl[2][64][64];   // 16 KB, V^T rows=d

    // staging addresses (unit u = shot*256 + tid; row = u>>3, phys chunk = u&7)
    const int rA = tid >> 3,        rB = 32 + (tid >> 3);
    const int lcA = (tid & 7) ^ (rA & 7), lcB = (tid & 7) ^ (rB & 7);
    const _Float16* KsrcA = Kp  + (size_t)rA*HD + lcA*8;
    const _Float16* KsrcB = Kp  + (size_t)rB*HD + lcB*8;
    const _Float16* VsrcA = Vpt + (size_t)rA*SEQ + lcA*8;
    const _Float16* VsrcB = Vpt + (size_t)rB*SEQ + lcB*8;

    // Q fragments (B-operand): lane holds Q[q = R+qi*16+r16][d' = ks*32+g*8..+7]
    const int R = q0 + w*32;
    f16x8 qfr[2][2];
    #pragma unroll
    for (int qi = 0; qi < 2; ++qi)
        #pragma unroll
        for (int ks = 0; ks < 2; ++ks)
            qfr[qi][ks] = *(const f16x8*)(Q + (size_t)(R + qi*16 + r16)*HD + ks*32 + g*8);

    // O^T accumulators: ofT[qi][n][r] = O^T[d = n*16+g*4+r][q = R+qi*16+r16]
    f32x4 ofT[2][4] = {};
    float mr[2] = {-INFINITY, -INFINITY}, lr[2] = {0.f, 0.f};

    const int nt = (q0 >> 6) + 2;
    const int permLo = r16 + 32*(g & 1);                 // shfl source lanes

    #define STAGE(buf, kv0) do {                                              \
        gload_lds16(KsrcA + (size_t)(kv0)*HD, &Kl[(buf)][0][0] + tid*8);      \
        gload_lds16(KsrcB + (size_t)(kv0)*HD, &Kl[(buf)][0][0] + (256+tid)*8);\
        gload_lds16(VsrcA + (kv0),            &Vl[(buf)][0][0] + tid*8);      \
        gload_lds16(VsrcB + (kv0),            &Vl[(buf)][0][0] + (256+tid)*8);\
    } while (0)

    STAGE(0, 0);
    for (int kt = 0; kt < nt; ++kt) {
        const int kv0 = kt << 6;
        __syncthreads();                         // buf[kt&1] ready; other buf free
        if (kt + 1 < nt) STAGE((kt + 1) & 1, (kt + 1) << 6);
        const int buf = kt & 1;

        if (kv0 <= R + 31) {                     // wave has unmasked work
            // ---- S^T = K Q^T : sT[qi][n][r] = S[q=r16+..][kv = kv0+n*16+g*4+r]
            f32x4 sT[2][4] = {};
            __builtin_amdgcn_s_setprio(1);
            #pragma unroll
            for (int ks = 0; ks < 2; ++ks) {
                f16x8 kf[4];
                #pragma unroll
                for (int n = 0; n < 4; ++n) {
                    int krow = n*16 + r16;
                    kf[n] = *(const f16x8*)&Kl[buf][krow][(((ks<<2)|g) ^ (krow & 7))*8];
                }
                #pragma unroll
                for (int qi = 0; qi < 2; ++qi)
                    #pragma unroll
                    for (int n = 0; n < 4; ++n)
                        sT[qi][n] = __builtin_amdgcn_mfma_f32_16x16x32_f16(kf[n], qfr[qi][ks], sT[qi][n], 0, 0, 0);
            }
            __builtin_amdgcn_s_setprio(0);

            // ---- in-register online softmax + P -> B-fragments ----
            uint breg[2][2][4];                  // [qi][ks][j2]
            #pragma unroll
            for (int qi = 0; qi < 2; ++qi) {
                const int q = R + qi*16 + r16;
                float sv[16];
                #pragma unroll
                for (int n = 0; n < 4; ++n)
                    #pragma unroll
                    for (int r = 0; r < 4; ++r)
                        sv[n*4 + r] = (kv0 + n*16 + g*4 + r <= q) ? sT[qi][n][r] : -INFINITY;
                float mx = sv[0];
                #pragma unroll
                for (int i = 1; i < 16; ++i) mx = fmaxf(mx, sv[i]);
                mx = fmaxf(mx, __shfl_xor(mx, 16));
                mx = fmaxf(mx, __shfl_xor(mx, 32));
                float mnew = fmaxf(mr[qi], mx);
                float al = __expf(mr[qi] - mnew);
                float ps = 0.f;
                #pragma unroll
                for (int i = 0; i < 16; ++i) { sv[i] = __expf(sv[i] - mnew); ps += sv[i]; }
                ps += __shfl_xor(ps, 16);
                ps += __shfl_xor(ps, 32);
                lr[qi] = lr[qi] * al + ps;
                mr[qi] = mnew;
                #pragma unroll
                for (int n = 0; n < 4; ++n) ofT[qi][n] *= al;

                // pack: pku[t][rp] holds P^T[k = kv0 + 16t + 4g + 2rp, +1][q]
                uint pku[4][2];
                #pragma unroll
                for (int t = 0; t < 4; ++t)
                    #pragma unroll
                    for (int rp = 0; rp < 2; ++rp) {
                        union { fp16x2 h; uint u; } cv;
                        cv.h = __builtin_amdgcn_cvt_pkrtz(sv[t*4 + 2*rp], sv[t*4 + 2*rp + 1]);
                        pku[t][rp] = cv.u;
                    }
                // permute to B-frag: lane needs k'' = 32ks + 8g + 2j2 from
                // lane permLo+16*(j2>>1), reg pk[2ks + (g>>1)][j2&1]
                #pragma unroll
                for (int ks = 0; ks < 2; ++ks)
                    #pragma unroll
                    for (int j2 = 0; j2 < 4; ++j2) {
                        int src = permLo + ((j2 >> 1) << 4);
                        int lo = __shfl((int)pku[2*ks    ][j2 & 1], src);
                        int hi = __shfl((int)pku[2*ks + 1][j2 & 1], src);
                        breg[qi][ks][j2] = (uint)((g & 2) ? hi : lo);
                    }
            }

            // ---- O^T += V^T P^T ----
            __builtin_amdgcn_s_setprio(1);
            #pragma unroll
            for (int ks = 0; ks < 2; ++ks) {
                f16x8 vf[4];
                #pragma unroll
                for (int n = 0; n < 4; ++n) {
                    int vrow = n*16 + r16;
                    vf[n] = *(const f16x8*)&Vl[buf][vrow][(((ks<<2)|g) ^ (vrow & 7))*8];
                }
                #pragma unroll
                for (int qi = 0; qi < 2; ++qi) {
                    union { uint u[4]; f16x8 h; } pb;
                    #pragma unroll
                    for (int j2 = 0; j2 < 4; ++j2) pb.u[j2] = breg[qi][ks][j2];
                    #pragma unroll
                    for (int n = 0; n < 4; ++n)
                        ofT[qi][n] = __builtin_amdgcn_mfma_f32_16x16x32_f16(vf[n], pb.h, ofT[qi][n], 0, 0, 0);
                }
            }
            __builtin_amdgcn_s_setprio(0);
        }
    }
    #undef STAGE

    // normalize + store: lane writes d = n*16+g*4 .. +3 (contiguous) for its q row
    const int b = bh >> 4, h = bh & 15;
    #pragma unroll
    for (int qi = 0; qi < 2; ++qi) {
        float inv = 1.0f / lr[qi];
        const int srow = R + qi*16 + r16;
        _Float16* dst = ao + ((size_t)(b*SEQ + srow))*DM + h*HD + g*4;
        #pragma unroll
        for (int n = 0; n < 4; ++n) {
            f16x4 pk4;
            #pragma unroll
            for (int r = 0; r < 4; ++r) pk4[r] = (_Float16)(ofT[qi][n][r] * inv);
            *(f16x4*)(dst + n*16) = pk4;
        }
    }
}

// ---------------- launcher ----------------
extern "C" void kernel_launch(void* const* d_in, const int* in_sizes, int n_in,
                              void* d_out, int out_size, void* d_ws, size_t ws_size,
                              hipStream_t stream) {
    const float* x  = (const float*)d_in[0];
    const int*   tp = (const int*)d_in[1];
    const float* wq = (const float*)d_in[2];
    const float* wk = (const float*)d_in[3];
    const float* wv = (const float*)d_in[4];
    const float* wo = (const float*)d_in[5];
    float* out = (float*)d_out;

    char* ws = (char*)d_ws;
    _Float16* xh  = (_Float16*)(ws);                         // 16,777,216 B
    _Float16* whq = (_Float16*)(ws + 16777216);              //  6,291,456 B (wq|wk|wv)
    _Float16* woh = (_Float16*)(ws + 23068672);              //  2,097,152 B
    _Float16* qkv = (_Float16*)(ws + 25165824);              // 50,331,648 B
    _Float16* ao  = (_Float16*)(ws + 75497472);              // 16,777,216 B
    float2*   rope= (float2*)  (ws + 92274688);              //    524,288 B  (total ~92.8 MB)

    f32_to_f16<<<MROWS*DM/1024, 256, 0, stream>>>(x, xh, MROWS*DM);
    f32_to_f16<<<DM*DM/1024, 256, 0, stream>>>(wq, whq,            DM*DM);
    f32_to_f16<<<DM*DM/1024, 256, 0, stream>>>(wk, whq + DM*DM,    DM*DM);
    f32_to_f16<<<DM*DM/1024, 256, 0, stream>>>(wv, whq + 2*DM*DM,  DM*DM);
    f32_to_f16<<<DM*DM/1024, 256, 0, stream>>>(wo, woh,            DM*DM);
    rope_table<<<SEQ*32/256, 256, 0, stream>>>(tp, rope);

    gemm_f16<1><<<dim3(MROWS/128, 3*DM/128), 256, 0, stream>>>(xh, whq, nullptr, qkv, rope);
    attn_kernel<<<dim3(SEQ/128, BATCH*NH), 256, 0, stream>>>(qkv, ao);
    gemm_f16<0><<<dim3(MROWS/128, DM/128), 256, 0, stream>>>(ao, woh, out, nullptr, nullptr);
}

// Round 5
// 227.108 us; speedup vs baseline: 2.3808x; 1.3357x over previous
//
#include <hip/hip_runtime.h>
#include <hip/hip_fp16.h>

#define DM   1024
#define NH   16
#define HD   64
#define BATCH 4
#define SEQ  2048
#define MROWS (BATCH*SEQ)            // 8192
#define BHSD  ((size_t)BATCH*NH*SEQ*HD)  // 8388608 elems

using f32x4 = __attribute__((ext_vector_type(4))) float;
using f16x8 = __attribute__((ext_vector_type(8))) _Float16;
using f16x4 = __attribute__((ext_vector_type(4))) _Float16;
using fp16x2 = __attribute__((ext_vector_type(2))) __fp16;

__device__ __forceinline__ void gload_lds16(const void* g, void* l) {
    __builtin_amdgcn_global_load_lds(
        (const __attribute__((address_space(1))) void*)g,
        (__attribute__((address_space(3))) void*)l, 16, 0, 0);
}

// ---------------- fp32 -> fp16 cast ----------------
__global__ __launch_bounds__(256) void f32_to_f16(const float* __restrict__ in,
                                                  _Float16* __restrict__ out, int n) {
    int i = (blockIdx.x * 256 + threadIdx.x) * 4;
    if (i >= n) return;
    float4 v = *(const float4*)(in + i);
    union { _Float16 h[4]; ushort4 u; } cv;
    cv.h[0] = (_Float16)v.x; cv.h[1] = (_Float16)v.y;
    cv.h[2] = (_Float16)v.z; cv.h[3] = (_Float16)v.w;
    *(ushort4*)(out + i) = cv.u;
}

// ---------------- RoPE cos/sin table: [SEQ][32] float2 ----------------
__global__ __launch_bounds__(256) void rope_table(const int* __restrict__ pos,
                                                  float2* __restrict__ tab) {
    int idx = blockIdx.x * 256 + threadIdx.x;    // 65536
    int s = idx >> 5, j = idx & 31;
    float p = (float)pos[s];
    float invf = powf(10000.0f, -(float)j / 32.0f);
    float ang = p * invf;
    tab[idx] = make_float2(cosf(ang), sinf(ang));
}

// ---------------- GEMM: C = A(MxK) * W^T, W row-major (N x K) ----------------
// MODE 0: write fp32 to outF (row-major MxN)
// MODE 1: fused RoPE epilogue -> q,k fp16 in [B][H][S][D]; V TRANSPOSED [B][H][D][S]
//         Q additionally scaled by 0.125*log2(e) so attention can use exp2.
template<int MODE>
__global__ __launch_bounds__(256)
void gemm_f16(const _Float16* __restrict__ A, const _Float16* __restrict__ Bw,
              float* __restrict__ outF, _Float16* __restrict__ qkv,
              const float2* __restrict__ rope) {
    __shared__ __align__(16) _Float16 lds[2][2][128][32];   // [dbuf][A/B][row][k] = 32 KiB
    const int tid  = threadIdx.x;
    const int lane = tid & 63;
    const int wid  = tid >> 6;
    const int m0 = blockIdx.x * 128;
    const int n0 = blockIdx.y * 128;
    const int wm = (wid >> 1) * 64;
    const int wn = (wid & 1) * 64;
    const int g   = lane >> 4;
    const int r16 = lane & 15;

    const int srow0 = (wid*2 + 0)*16 + (lane >> 2);
    const int srow1 = (wid*2 + 1)*16 + (lane >> 2);
    const int sch0 = (lane & 3) ^ ((srow0 >> 1) & 3);
    const int sch1 = (lane & 3) ^ ((srow1 >> 1) & 3);
    const _Float16* Asrc0 = A  + (size_t)(m0 + srow0)*DM + sch0*8;
    const _Float16* Asrc1 = A  + (size_t)(m0 + srow1)*DM + sch1*8;
    const _Float16* Bsrc0 = Bw + (size_t)(n0 + srow0)*DM + sch0*8;
    const _Float16* Bsrc1 = Bw + (size_t)(n0 + srow1)*DM + sch1*8;

    f32x4 acc[4][4] = {};

    #define STAGE(buf, kt) do {                                           \
        const int koff = (kt)*32;                                         \
        _Float16* bA = &lds[(buf)][0][0][0];                              \
        _Float16* bB = &lds[(buf)][1][0][0];                              \
        gload_lds16(Asrc0 + koff, bA + (wid*2 + 0)*512);                  \
        gload_lds16(Asrc1 + koff, bA + (wid*2 + 1)*512);                  \
        gload_lds16(Bsrc0 + koff, bB + (wid*2 + 0)*512);                  \
        gload_lds16(Bsrc1 + koff, bB + (wid*2 + 1)*512);                  \
    } while (0)

    STAGE(0, 0);
    for (int kt = 0; kt < 32; ++kt) {
        __syncthreads();
        if (kt + 1 < 32) STAGE((kt + 1) & 1, kt + 1);
        const int buf = kt & 1;
        f16x8 af[4], bf[4];
        #pragma unroll
        for (int i = 0; i < 4; ++i) {
            int rowa = wm + i*16 + r16;
            af[i] = *(const f16x8*)&lds[buf][0][rowa][(g ^ ((rowa >> 1) & 3)) * 8];
            int rowb = wn + i*16 + r16;
            bf[i] = *(const f16x8*)&lds[buf][1][rowb][(g ^ ((rowb >> 1) & 3)) * 8];
        }
        #pragma unroll
        for (int i = 0; i < 4; ++i)
            #pragma unroll
            for (int j = 0; j < 4; ++j)
                acc[i][j] = __builtin_amdgcn_mfma_f32_16x16x32_f16(af[i], bf[j], acc[i][j], 0, 0, 0);
    }
    #undef STAGE

    // epilogue
    #pragma unroll
    for (int i = 0; i < 4; ++i) {
        #pragma unroll
        for (int j = 0; j < 4; ++j) {
            if constexpr (MODE == 0) {
                #pragma unroll
                for (int r = 0; r < 4; ++r) {
                    const int m = m0 + wm + i*16 + g*4 + r;
                    const int n = n0 + wn + j*16 + r16;
                    outF[(size_t)m*DM + n] = acc[i][j][r];
                }
            } else {
                const int n = n0 + wn + j*16 + r16;
                const int sel = n >> 10;              // 0=q 1=k 2=v (block-uniform)
                const int cc = n & 1023;
                const int h = cc >> 6, dd = cc & 63;
                if (sel == 2) {
                    // V^T: 4 consecutive s (r=0..3) at fixed d -> one 8B store
                    const int mb = m0 + wm + i*16 + g*4;
                    const int s0 = mb & (SEQ - 1), b = mb >> 11;
                    f16x4 pk;
                    #pragma unroll
                    for (int r = 0; r < 4; ++r) pk[r] = (_Float16)acc[i][j][r];
                    *(f16x4*)(qkv + 2*BHSD + ((size_t)((b*NH + h)*HD + dd))*SEQ + s0) = pk;
                } else {
                    #pragma unroll
                    for (int r = 0; r < 4; ++r) {
                        const int m = m0 + wm + i*16 + g*4 + r;
                        float v = acc[i][j][r];
                        float vp = __shfl_xor(v, 1);          // partner column (n^1)
                        const int s = m & (SEQ - 1), b = m >> 11;
                        float2 cs = rope[(s << 5) + (dd >> 1)];
                        float o;
                        if (dd & 1) o = vp * cs.y + v * cs.x;   // x1*sin + x2*cos
                        else        o = v * cs.x - vp * cs.y;   // x1*cos - x2*sin
                        if (sel == 0) o *= 0.18033688f;         // 1/sqrt(HD) * log2(e)
                        qkv[(size_t)sel*BHSD + ((size_t)((b*NH + h)*SEQ + s))*HD + dd] = (_Float16)o;
                    }
                }
            }
        }
    }
}

// ---------------- per-KV-tile attention step (swapped QK^T, in-register softmax) ----------
// Scores are in log2 domain (Q pre-scaled by 0.125*log2e); exp2 everywhere.
__device__ __forceinline__ void process_tile(
    const _Float16 (*__restrict__ Klb)[64], const _Float16 (*__restrict__ Vlb)[64],
    const f16x8 (&qf)[2][2], f32x4 (&ot)[2][4], float (&m)[2], float (&l)[2],
    const int Rq, const int kv0, const int g, const int r16, const int permLo) {

    // ---- S^T = K Q^T : sT[qi][n][r] = S[q = Rq+qi*16+r16][kv = kv0+n*16+g*4+r]
    f32x4 sT[2][4] = {};
    const int kchunkBase = r16 & 7;
    __builtin_amdgcn_s_setprio(1);
    #pragma unroll
    for (int ks = 0; ks < 2; ++ks) {
        f16x8 kf[4];
        #pragma unroll
        for (int n = 0; n < 4; ++n)
            kf[n] = *(const f16x8*)&Klb[n*16 + r16][(((ks<<2)|g) ^ kchunkBase)*8];
        #pragma unroll
        for (int qi = 0; qi < 2; ++qi)
            #pragma unroll
            for (int n = 0; n < 4; ++n)
                sT[qi][n] = __builtin_amdgcn_mfma_f32_16x16x32_f16(kf[n], qf[qi][ks], sT[qi][n], 0, 0, 0);
    }
    __builtin_amdgcn_s_setprio(0);

    // ---- online softmax (log2 domain) + P -> B-fragments ----
    uint breg[2][2][4];
    #pragma unroll
    for (int qi = 0; qi < 2; ++qi) {
        const bool full = (kv0 + 63 <= Rq + qi*16);      // wave-uniform
        float sv[16];
        if (full) {
            #pragma unroll
            for (int n = 0; n < 4; ++n)
                #pragma unroll
                for (int r = 0; r < 4; ++r) sv[n*4 + r] = sT[qi][n][r];
        } else {
            const int q = Rq + qi*16 + r16;
            #pragma unroll
            for (int n = 0; n < 4; ++n)
                #pragma unroll
                for (int r = 0; r < 4; ++r)
                    sv[n*4 + r] = (kv0 + n*16 + g*4 + r <= q) ? sT[qi][n][r] : -INFINITY;
        }
        float mx = sv[0];
        #pragma unroll
        for (int i = 1; i < 16; ++i) mx = fmaxf(mx, sv[i]);
        mx = fmaxf(mx, __shfl_xor(mx, 16));
        mx = fmaxf(mx, __shfl_xor(mx, 32));
        // defer-max (T13): only rescale when max grew by > 8 (log2 units -> P <= 256)
        const bool need = (mx > m[qi] + 8.f);
        if (__any(need)) {
            float mnew = need ? mx : m[qi];
            float al = exp2f(m[qi] - mnew);
            m[qi] = mnew;
            l[qi] *= al;
            #pragma unroll
            for (int n = 0; n < 4; ++n) ot[qi][n] *= al;
        }
        float ps = 0.f;
        #pragma unroll
        for (int i = 0; i < 16; ++i) { sv[i] = exp2f(sv[i] - m[qi]); ps += sv[i]; }
        ps += __shfl_xor(ps, 16);
        ps += __shfl_xor(ps, 32);
        l[qi] += ps;

        // pack + permute to PV B-fragment layout
        uint pku[4][2];
        #pragma unroll
        for (int t = 0; t < 4; ++t)
            #pragma unroll
            for (int rp = 0; rp < 2; ++rp) {
                union { fp16x2 h; uint u; } cv;
                cv.h = __builtin_amdgcn_cvt_pkrtz(sv[t*4 + 2*rp], sv[t*4 + 2*rp + 1]);
                pku[t][rp] = cv.u;
            }
        #pragma unroll
        for (int ks = 0; ks < 2; ++ks)
            #pragma unroll
            for (int j2 = 0; j2 < 4; ++j2) {
                int src = permLo + ((j2 >> 1) << 4);
                int lo = __shfl((int)pku[2*ks    ][j2 & 1], src);
                int hi = __shfl((int)pku[2*ks + 1][j2 & 1], src);
                breg[qi][ks][j2] = (uint)((g & 2) ? hi : lo);
            }
    }

    // ---- O^T += V^T P^T ----
    __builtin_amdgcn_s_setprio(1);
    #pragma unroll
    for (int ks = 0; ks < 2; ++ks) {
        f16x8 vf[4];
        #pragma unroll
        for (int n = 0; n < 4; ++n)
            vf[n] = *(const f16x8*)&Vlb[n*16 + r16][(((ks<<2)|g) ^ kchunkBase)*8];
        #pragma unroll
        for (int qi = 0; qi < 2; ++qi) {
            union { uint u[4]; f16x8 h; } pb;
            #pragma unroll
            for (int j2 = 0; j2 < 4; ++j2) pb.u[j2] = breg[qi][ks][j2];
            #pragma unroll
            for (int n = 0; n < 4; ++n)
                ot[qi][n] = __builtin_amdgcn_mfma_f32_16x16x32_f16(vf[n], pb.h, ot[qi][n], 0, 0, 0);
        }
    }
    __builtin_amdgcn_s_setprio(0);
}

// ---------------- flash attention: diagonal-paired q-tiles for load balance ----------------
// Block (bh, j): processes q-tile hi = 15-j AND q-tile lo = j (uniform 34 tile-computes).
// Staged K/V tiles are shared by both q-tiles. 4 waves, 32 q-rows per wave per q-tile.
__global__ __launch_bounds__(256, 2)
void attn_kernel(const _Float16* __restrict__ qkv, _Float16* __restrict__ ao) {
    const int tid = threadIdx.x, lane = tid & 63, w = tid >> 6;
    const int g = lane >> 4, r16 = lane & 15;
    const int bh = blockIdx.x;                       // id%8 == bh%8 -> same bh, same XCD
    const int jq = blockIdx.y;                       // 0..7
    const int q0h = (15 - jq) * 128, q0l = jq * 128;
    const _Float16* Q   = qkv + (size_t)bh * SEQ * HD;
    const _Float16* Kp  = qkv + BHSD + (size_t)bh * SEQ * HD;
    const _Float16* Vpt = qkv + 2*BHSD + (size_t)bh * SEQ * HD;   // [d][s]

    __shared__ __align__(16) _Float16 Kl[2][64][64];   // 16 KB
    __shared__ __align__(16) _Float16 Vl[2][64][64];   // 16 KB

    // staging addresses (unit u = shot*256 + tid; row = u>>3, phys chunk = u&7)
    const int rA = tid >> 3,        rB = 32 + (tid >> 3);
    const int lcA = (tid & 7) ^ (rA & 7), lcB = (tid & 7) ^ (rB & 7);
    const _Float16* KsrcA = Kp  + (size_t)rA*HD + lcA*8;
    const _Float16* KsrcB = Kp  + (size_t)rB*HD + lcB*8;
    const _Float16* VsrcA = Vpt + (size_t)rA*SEQ + lcA*8;
    const _Float16* VsrcB = Vpt + (size_t)rB*SEQ + lcB*8;

    const int Rh = q0h + w*32, Rl = q0l + w*32;
    f16x8 qfh[2][2], qfl[2][2];
    #pragma unroll
    for (int qi = 0; qi < 2; ++qi)
        #pragma unroll
        for (int ks = 0; ks < 2; ++ks) {
            qfh[qi][ks] = *(const f16x8*)(Q + (size_t)(Rh + qi*16 + r16)*HD + ks*32 + g*8);
            qfl[qi][ks] = *(const f16x8*)(Q + (size_t)(Rl + qi*16 + r16)*HD + ks*32 + g*8);
        }

    f32x4 oth[2][4] = {}, otl[2][4] = {};
    float mh[2] = {-INFINITY, -INFINITY}, lh[2] = {0.f, 0.f};
    float ml[2] = {-INFINITY, -INFINITY}, ll[2] = {0.f, 0.f};

    const int nth = (q0h >> 6) + 2;                  // staged tiles (hi coverage)
    const int ntl = (q0l >> 6) + 2;                  // lo-compute tiles
    const int permLo = r16 + 32*(g & 1);

    #define STAGE(buf, kv0) do {                                              \
        gload_lds16(KsrcA + (size_t)(kv0)*HD, &Kl[(buf)][0][0] + tid*8);      \
        gload_lds16(KsrcB + (size_t)(kv0)*HD, &Kl[(buf)][0][0] + (256+tid)*8);\
        gload_lds16(VsrcA + (kv0),            &Vl[(buf)][0][0] + tid*8);      \
        gload_lds16(VsrcB + (kv0),            &Vl[(buf)][0][0] + (256+tid)*8);\
    } while (0)

    STAGE(0, 0);
    for (int kt = 0; kt < nth; ++kt) {
        const int kv0 = kt << 6;
        __syncthreads();                             // buf[kt&1] ready; other buf free
        if (kt + 1 < nth) STAGE((kt + 1) & 1, (kt + 1) << 6);
        const int buf = kt & 1;

        if (kv0 <= Rh + 31)
            process_tile(Kl[buf], Vl[buf], qfh, oth, mh, lh, Rh, kv0, g, r16, permLo);
        if (kt < ntl && kv0 <= Rl + 31)
            process_tile(Kl[buf], Vl[buf], qfl, otl, ml, ll, Rl, kv0, g, r16, permLo);
    }
    #undef STAGE

    // normalize + store both q-tiles: lane writes d = n*16+g*4 .. +3 for its q row
    const int b = bh >> 4, h = bh & 15;
    #pragma unroll
    for (int qi = 0; qi < 2; ++qi) {
        float invh = 1.0f / lh[qi], invl = 1.0f / ll[qi];
        const int srh = Rh + qi*16 + r16, srl = Rl + qi*16 + r16;
        _Float16* dsth = ao + ((size_t)(b*SEQ + srh))*DM + h*HD + g*4;
        _Float16* dstl = ao + ((size_t)(b*SEQ + srl))*DM + h*HD + g*4;
        #pragma unroll
        for (int n = 0; n < 4; ++n) {
            f16x4 pkh, pkl;
            #pragma unroll
            for (int r = 0; r < 4; ++r) {
                pkh[r] = (_Float16)(oth[qi][n][r] * invh);
                pkl[r] = (_Float16)(otl[qi][n][r] * invl);
            }
            *(f16x4*)(dsth + n*16) = pkh;
            *(f16x4*)(dstl + n*16) = pkl;
        }
    }
}

// ---------------- launcher ----------------
extern "C" void kernel_launch(void* const* d_in, const int* in_sizes, int n_in,
                              void* d_out, int out_size, void* d_ws, size_t ws_size,
                              hipStream_t stream) {
    const float* x  = (const float*)d_in[0];
    const int*   tp = (const int*)d_in[1];
    const float* wq = (const float*)d_in[2];
    const float* wk = (const float*)d_in[3];
    const float* wv = (const float*)d_in[4];
    const float* wo = (const float*)d_in[5];
    float* out = (float*)d_out;

    char* ws = (char*)d_ws;
    _Float16* xh  = (_Float16*)(ws);                         // 16,777,216 B
    _Float16* whq = (_Float16*)(ws + 16777216);              //  6,291,456 B (wq|wk|wv)
    _Float16* woh = (_Float16*)(ws + 23068672);              //  2,097,152 B
    _Float16* qkv = (_Float16*)(ws + 25165824);              // 50,331,648 B
    _Float16* ao  = (_Float16*)(ws + 75497472);              // 16,777,216 B
    float2*   rope= (float2*)  (ws + 92274688);              //    524,288 B  (total ~92.8 MB)

    f32_to_f16<<<MROWS*DM/1024, 256, 0, stream>>>(x, xh, MROWS*DM);
    f32_to_f16<<<DM*DM/1024, 256, 0, stream>>>(wq, whq,            DM*DM);
    f32_to_f16<<<DM*DM/1024, 256, 0, stream>>>(wk, whq + DM*DM,    DM*DM);
    f32_to_f16<<<DM*DM/1024, 256, 0, stream>>>(wv, whq + 2*DM*DM,  DM*DM);
    f32_to_f16<<<DM*DM/1024, 256, 0, stream>>>(wo, woh,            DM*DM);
    rope_table<<<SEQ*32/256, 256, 0, stream>>>(tp, rope);

    gemm_f16<1><<<dim3(MROWS/128, 3*DM/128), 256, 0, stream>>>(xh, whq, nullptr, qkv, rope);
    attn_kernel<<<dim3(BATCH*NH, SEQ/256), 256, 0, stream>>>(qkv, ao);
    gemm_f16<0><<<dim3(MROWS/128, DM/128), 256, 0, stream>>>(ao, woh, out, nullptr, nullptr);
}

// Round 6
// 223.000 us; speedup vs baseline: 2.4247x; 1.0184x over previous
//
#include <hip/hip_runtime.h>
#include <hip/hip_fp16.h>

#define DM   1024
#define NH   16
#define HD   64
#define BATCH 4
#define SEQ  2048
#define MROWS (BATCH*SEQ)            // 8192
#define BHSD  ((size_t)BATCH*NH*SEQ*HD)  // 8388608 elems

using f32x4 = __attribute__((ext_vector_type(4))) float;
using f16x8 = __attribute__((ext_vector_type(8))) _Float16;
using f16x4 = __attribute__((ext_vector_type(4))) _Float16;
using fp16x2 = __attribute__((ext_vector_type(2))) __fp16;

__device__ __forceinline__ void gload_lds16(const void* g, void* l) {
    __builtin_amdgcn_global_load_lds(
        (const __attribute__((address_space(1))) void*)g,
        (__attribute__((address_space(3))) void*)l, 16, 0, 0);
}

// ---------------- fp32 -> fp16 cast ----------------
__global__ __launch_bounds__(256) void f32_to_f16(const float* __restrict__ in,
                                                  _Float16* __restrict__ out, int n) {
    int i = (blockIdx.x * 256 + threadIdx.x) * 4;
    if (i >= n) return;
    float4 v = *(const float4*)(in + i);
    union { _Float16 h[4]; ushort4 u; } cv;
    cv.h[0] = (_Float16)v.x; cv.h[1] = (_Float16)v.y;
    cv.h[2] = (_Float16)v.z; cv.h[3] = (_Float16)v.w;
    *(ushort4*)(out + i) = cv.u;
}

// ---------------- RoPE cos/sin table: [SEQ][32] float2 ----------------
__global__ __launch_bounds__(256) void rope_table(const int* __restrict__ pos,
                                                  float2* __restrict__ tab) {
    int idx = blockIdx.x * 256 + threadIdx.x;    // 65536
    int s = idx >> 5, j = idx & 31;
    float p = (float)pos[s];
    float invf = powf(10000.0f, -(float)j / 32.0f);
    float ang = p * invf;
    tab[idx] = make_float2(cosf(ang), sinf(ang));
}

// ---------------- GEMM: C = A(MxK) * W^T, W row-major (N x K) ----------------
// MODE 0: write fp32 to outF (row-major MxN)
// MODE 1: fused RoPE epilogue -> q,k fp16 in [B][H][S][D]; V TRANSPOSED [B][H][D][S]
//         Q additionally scaled by 0.125*log2(e) so attention can use exp2.
template<int MODE>
__global__ __launch_bounds__(256)
void gemm_f16(const _Float16* __restrict__ A, const _Float16* __restrict__ Bw,
              float* __restrict__ outF, _Float16* __restrict__ qkv,
              const float2* __restrict__ rope) {
    __shared__ __align__(16) _Float16 lds[2][2][128][32];   // [dbuf][A/B][row][k] = 32 KiB
    const int tid  = threadIdx.x;
    const int lane = tid & 63;
    const int wid  = tid >> 6;
    const int m0 = blockIdx.x * 128;
    const int n0 = blockIdx.y * 128;
    const int wm = (wid >> 1) * 64;
    const int wn = (wid & 1) * 64;
    const int g   = lane >> 4;
    const int r16 = lane & 15;

    const int srow0 = (wid*2 + 0)*16 + (lane >> 2);
    const int srow1 = (wid*2 + 1)*16 + (lane >> 2);
    const int sch0 = (lane & 3) ^ ((srow0 >> 1) & 3);
    const int sch1 = (lane & 3) ^ ((srow1 >> 1) & 3);
    const _Float16* Asrc0 = A  + (size_t)(m0 + srow0)*DM + sch0*8;
    const _Float16* Asrc1 = A  + (size_t)(m0 + srow1)*DM + sch1*8;
    const _Float16* Bsrc0 = Bw + (size_t)(n0 + srow0)*DM + sch0*8;
    const _Float16* Bsrc1 = Bw + (size_t)(n0 + srow1)*DM + sch1*8;

    f32x4 acc[4][4] = {};

    #define STAGE(buf, kt) do {                                           \
        const int koff = (kt)*32;                                         \
        _Float16* bA = &lds[(buf)][0][0][0];                              \
        _Float16* bB = &lds[(buf)][1][0][0];                              \
        gload_lds16(Asrc0 + koff, bA + (wid*2 + 0)*512);                  \
        gload_lds16(Asrc1 + koff, bA + (wid*2 + 1)*512);                  \
        gload_lds16(Bsrc0 + koff, bB + (wid*2 + 0)*512);                  \
        gload_lds16(Bsrc1 + koff, bB + (wid*2 + 1)*512);                  \
    } while (0)

    STAGE(0, 0);
    for (int kt = 0; kt < 32; ++kt) {
        __syncthreads();
        if (kt + 1 < 32) STAGE((kt + 1) & 1, kt + 1);
        const int buf = kt & 1;
        f16x8 af[4], bf[4];
        #pragma unroll
        for (int i = 0; i < 4; ++i) {
            int rowa = wm + i*16 + r16;
            af[i] = *(const f16x8*)&lds[buf][0][rowa][(g ^ ((rowa >> 1) & 3)) * 8];
            int rowb = wn + i*16 + r16;
            bf[i] = *(const f16x8*)&lds[buf][1][rowb][(g ^ ((rowb >> 1) & 3)) * 8];
        }
        #pragma unroll
        for (int i = 0; i < 4; ++i)
            #pragma unroll
            for (int j = 0; j < 4; ++j)
                acc[i][j] = __builtin_amdgcn_mfma_f32_16x16x32_f16(af[i], bf[j], acc[i][j], 0, 0, 0);
    }
    #undef STAGE

    // epilogue
    #pragma unroll
    for (int i = 0; i < 4; ++i) {
        #pragma unroll
        for (int j = 0; j < 4; ++j) {
            if constexpr (MODE == 0) {
                #pragma unroll
                for (int r = 0; r < 4; ++r) {
                    const int m = m0 + wm + i*16 + g*4 + r;
                    const int n = n0 + wn + j*16 + r16;
                    outF[(size_t)m*DM + n] = acc[i][j][r];
                }
            } else {
                const int n = n0 + wn + j*16 + r16;
                const int sel = n >> 10;              // 0=q 1=k 2=v (block-uniform)
                const int cc = n & 1023;
                const int h = cc >> 6, dd = cc & 63;
                if (sel == 2) {
                    // V^T: 4 consecutive s (r=0..3) at fixed d -> one 8B store
                    const int mb = m0 + wm + i*16 + g*4;
                    const int s0 = mb & (SEQ - 1), b = mb >> 11;
                    f16x4 pk;
                    #pragma unroll
                    for (int r = 0; r < 4; ++r) pk[r] = (_Float16)acc[i][j][r];
                    *(f16x4*)(qkv + 2*BHSD + ((size_t)((b*NH + h)*HD + dd))*SEQ + s0) = pk;
                } else {
                    #pragma unroll
                    for (int r = 0; r < 4; ++r) {
                        const int m = m0 + wm + i*16 + g*4 + r;
                        float v = acc[i][j][r];
                        float vp = __shfl_xor(v, 1);          // partner column (n^1)
                        const int s = m & (SEQ - 1), b = m >> 11;
                        float2 cs = rope[(s << 5) + (dd >> 1)];
                        float o;
                        if (dd & 1) o = vp * cs.y + v * cs.x;   // x1*sin + x2*cos
                        else        o = v * cs.x - vp * cs.y;   // x1*cos - x2*sin
                        if (sel == 0) o *= 0.18033688f;         // 1/sqrt(HD) * log2(e)
                        qkv[(size_t)sel*BHSD + ((size_t)((b*NH + h)*SEQ + s))*HD + dd] = (_Float16)o;
                    }
                }
            }
        }
    }
}

// ---------------- per-KV-tile attention step (swapped QK^T, in-register softmax) ----------
// Scores in log2 domain (Q pre-scaled by 0.125*log2e); exp2 everywhere.
// Wave owns 16 q rows (q = Rq + r16). KV tile = 64.
__device__ __forceinline__ void process_tile(
    const _Float16 (*__restrict__ Klb)[64], const _Float16 (*__restrict__ Vlb)[64],
    const f16x8 (&qf)[2], f32x4 (&ot)[4], float &m, float &l,
    const int Rq, const int kv0, const int g, const int r16, const int permLo) {

    // ---- S^T = K Q^T : sT[n][r] = S[q = Rq+r16][kv = kv0+n*16+g*4+r]
    f32x4 sT[4] = {};
    const int kchunkBase = r16 & 7;
    __builtin_amdgcn_s_setprio(1);
    #pragma unroll
    for (int ks = 0; ks < 2; ++ks) {
        #pragma unroll
        for (int n = 0; n < 4; ++n) {
            f16x8 kf = *(const f16x8*)&Klb[n*16 + r16][(((ks<<2)|g) ^ kchunkBase)*8];
            sT[n] = __builtin_amdgcn_mfma_f32_16x16x32_f16(kf, qf[ks], sT[n], 0, 0, 0);
        }
    }
    __builtin_amdgcn_s_setprio(0);

    // ---- online softmax (log2 domain) ----
    const bool full = (kv0 + 63 <= Rq);          // wave-uniform
    float sv[16];
    if (full) {
        #pragma unroll
        for (int n = 0; n < 4; ++n)
            #pragma unroll
            for (int r = 0; r < 4; ++r) sv[n*4 + r] = sT[n][r];
    } else {
        const int q = Rq + r16;
        #pragma unroll
        for (int n = 0; n < 4; ++n)
            #pragma unroll
            for (int r = 0; r < 4; ++r)
                sv[n*4 + r] = (kv0 + n*16 + 4*g + r <= q) ? sT[n][r] : -INFINITY;
    }
    float mx = sv[0];
    #pragma unroll
    for (int i = 1; i < 16; ++i) mx = fmaxf(mx, sv[i]);
    mx = fmaxf(mx, __shfl_xor(mx, 16));
    mx = fmaxf(mx, __shfl_xor(mx, 32));
    // defer-max (T13): rescale only when max grew by > 8 (log2 units -> P <= 256)
    const bool need = (mx > m + 8.f);
    if (__any(need)) {
        float mnew = need ? mx : m;
        float al = exp2f(m - mnew);
        m = mnew;
        l *= al;
        #pragma unroll
        for (int n = 0; n < 4; ++n) ot[n] *= al;
    }
    float ps = 0.f;
    #pragma unroll
    for (int i = 0; i < 16; ++i) { sv[i] = exp2f(sv[i] - m); ps += sv[i]; }
    ps += __shfl_xor(ps, 16);
    ps += __shfl_xor(ps, 32);
    l += ps;

    // ---- pack + permute P to PV B-fragment layout ----
    uint pku[4][2];
    #pragma unroll
    for (int t = 0; t < 4; ++t)
        #pragma unroll
        for (int rp = 0; rp < 2; ++rp) {
            union { fp16x2 h; uint u; } cv;
            cv.h = __builtin_amdgcn_cvt_pkrtz(sv[t*4 + 2*rp], sv[t*4 + 2*rp + 1]);
            pku[t][rp] = cv.u;
        }
    uint breg[2][4];
    #pragma unroll
    for (int ks = 0; ks < 2; ++ks)
        #pragma unroll
        for (int j2 = 0; j2 < 4; ++j2) {
            int src = permLo + ((j2 >> 1) << 4);
            int lo = __shfl((int)pku[2*ks    ][j2 & 1], src);
            int hi = __shfl((int)pku[2*ks + 1][j2 & 1], src);
            breg[ks][j2] = (uint)((g & 2) ? hi : lo);
        }

    // ---- O^T += V^T P^T ----
    __builtin_amdgcn_s_setprio(1);
    #pragma unroll
    for (int ks = 0; ks < 2; ++ks) {
        union { uint u[4]; f16x8 h; } pb;
        #pragma unroll
        for (int j2 = 0; j2 < 4; ++j2) pb.u[j2] = breg[ks][j2];
        #pragma unroll
        for (int n = 0; n < 4; ++n) {
            f16x8 vf = *(const f16x8*)&Vlb[n*16 + r16][(((ks<<2)|g) ^ kchunkBase)*8];
            ot[n] = __builtin_amdgcn_mfma_f32_16x16x32_f16(vf, pb.h, ot[n], 0, 0, 0);
        }
    }
    __builtin_amdgcn_s_setprio(0);
}

// ---------------- flash attention: diagonal-paired 64-row q-tiles, 16 q/wave ----------------
// Block (bh, j): q-tile hi = 31-j AND q-tile lo = j (uniform ~33 tile-computes).
// 1024 blocks -> 4 blocks/CU -> 4 waves/SIMD for latency hiding.
__global__ __launch_bounds__(256, 4)
void attn_kernel(const _Float16* __restrict__ qkv, _Float16* __restrict__ ao) {
    const int tid = threadIdx.x, lane = tid & 63, w = tid >> 6;
    const int g = lane >> 4, r16 = lane & 15;
    const int bh = blockIdx.x;                       // id%8 == bh%8 -> same bh, same XCD
    const int jq = blockIdx.y;                       // 0..15
    const int q0h = (31 - jq) * 64, q0l = jq * 64;
    const _Float16* Q   = qkv + (size_t)bh * SEQ * HD;
    const _Float16* Kp  = qkv + BHSD + (size_t)bh * SEQ * HD;
    const _Float16* Vpt = qkv + 2*BHSD + (size_t)bh * SEQ * HD;   // [d][s]

    __shared__ __align__(16) _Float16 Kl[2][64][64];   // 16 KB
    __shared__ __align__(16) _Float16 Vl[2][64][64];   // 16 KB

    // staging addresses (unit u = shot*256 + tid; row = u>>3, phys chunk = u&7)
    const int rA = tid >> 3,        rB = 32 + (tid >> 3);
    const int lcA = (tid & 7) ^ (rA & 7), lcB = (tid & 7) ^ (rB & 7);
    const _Float16* KsrcA = Kp  + (size_t)rA*HD + lcA*8;
    const _Float16* KsrcB = Kp  + (size_t)rB*HD + lcB*8;
    const _Float16* VsrcA = Vpt + (size_t)rA*SEQ + lcA*8;
    const _Float16* VsrcB = Vpt + (size_t)rB*SEQ + lcB*8;

    const int Rh = q0h + w*16, Rl = q0l + w*16;
    f16x8 qfh[2], qfl[2];
    #pragma unroll
    for (int ks = 0; ks < 2; ++ks) {
        qfh[ks] = *(const f16x8*)(Q + (size_t)(Rh + r16)*HD + ks*32 + g*8);
        qfl[ks] = *(const f16x8*)(Q + (size_t)(Rl + r16)*HD + ks*32 + g*8);
    }

    f32x4 oth[4] = {}, otl[4] = {};
    float mh = -INFINITY, lh = 0.f, ml_ = -INFINITY, ll_ = 0.f;

    const int nth = (q0h >> 6) + 1;                  // staged tiles (covers hi q-tile)
    const int ntl = (q0l >> 6) + 1;                  // lo-compute tiles
    const int permLo = r16 + 32*(g & 1);

    #define STAGE(buf, kv0) do {                                              \
        gload_lds16(KsrcA + (size_t)(kv0)*HD, &Kl[(buf)][0][0] + tid*8);      \
        gload_lds16(KsrcB + (size_t)(kv0)*HD, &Kl[(buf)][0][0] + (256+tid)*8);\
        gload_lds16(VsrcA + (kv0),            &Vl[(buf)][0][0] + tid*8);      \
        gload_lds16(VsrcB + (kv0),            &Vl[(buf)][0][0] + (256+tid)*8);\
    } while (0)

    STAGE(0, 0);
    for (int kt = 0; kt < nth; ++kt) {
        const int kv0 = kt << 6;
        __syncthreads();                             // buf[kt&1] ready; other buf free
        if (kt + 1 < nth) STAGE((kt + 1) & 1, (kt + 1) << 6);
        const int buf = kt & 1;

        if (kv0 <= Rh + 15)
            process_tile(Kl[buf], Vl[buf], qfh, oth, mh, lh, Rh, kv0, g, r16, permLo);
        if (kt < ntl)
            process_tile(Kl[buf], Vl[buf], qfl, otl, ml_, ll_, Rl, kv0, g, r16, permLo);
    }
    #undef STAGE

    // normalize + store both q-tiles: lane writes d = n*16+g*4 .. +3 for its q row
    const int b = bh >> 4, h = bh & 15;
    const float invh = 1.0f / lh, invl = 1.0f / ll_;
    _Float16* dsth = ao + ((size_t)(b*SEQ + Rh + r16))*DM + h*HD + g*4;
    _Float16* dstl = ao + ((size_t)(b*SEQ + Rl + r16))*DM + h*HD + g*4;
    #pragma unroll
    for (int n = 0; n < 4; ++n) {
        f16x4 pkh, pkl;
        #pragma unroll
        for (int r = 0; r < 4; ++r) {
            pkh[r] = (_Float16)(oth[n][r] * invh);
            pkl[r] = (_Float16)(otl[n][r] * invl);
        }
        *(f16x4*)(dsth + n*16) = pkh;
        *(f16x4*)(dstl + n*16) = pkl;
    }
}

// ---------------- launcher ----------------
extern "C" void kernel_launch(void* const* d_in, const int* in_sizes, int n_in,
                              void* d_out, int out_size, void* d_ws, size_t ws_size,
                              hipStream_t stream) {
    const float* x  = (const float*)d_in[0];
    const int*   tp = (const int*)d_in[1];
    const float* wq = (const float*)d_in[2];
    const float* wk = (const float*)d_in[3];
    const float* wv = (const float*)d_in[4];
    const float* wo = (const float*)d_in[5];
    float* out = (float*)d_out;

    char* ws = (char*)d_ws;
    _Float16* xh  = (_Float16*)(ws);                         // 16,777,216 B
    _Float16* whq = (_Float16*)(ws + 16777216);              //  6,291,456 B (wq|wk|wv)
    _Float16* woh = (_Float16*)(ws + 23068672);              //  2,097,152 B
    _Float16* qkv = (_Float16*)(ws + 25165824);              // 50,331,648 B
    _Float16* ao  = (_Float16*)(ws + 75497472);              // 16,777,216 B
    float2*   rope= (float2*)  (ws + 92274688);              //    524,288 B  (total ~92.8 MB)

    f32_to_f16<<<MROWS*DM/1024, 256, 0, stream>>>(x, xh, MROWS*DM);
    f32_to_f16<<<DM*DM/1024, 256, 0, stream>>>(wq, whq,            DM*DM);
    f32_to_f16<<<DM*DM/1024, 256, 0, stream>>>(wk, whq + DM*DM,    DM*DM);
    f32_to_f16<<<DM*DM/1024, 256, 0, stream>>>(wv, whq + 2*DM*DM,  DM*DM);
    f32_to_f16<<<DM*DM/1024, 256, 0, stream>>>(wo, woh,            DM*DM);
    rope_table<<<SEQ*32/256, 256, 0, stream>>>(tp, rope);

    gemm_f16<1><<<dim3(MROWS/128, 3*DM/128), 256, 0, stream>>>(xh, whq, nullptr, qkv, rope);
    attn_kernel<<<dim3(BATCH*NH, 16), 256, 0, stream>>>(qkv, ao);
    gemm_f16<0><<<dim3(MROWS/128, DM/128), 256, 0, stream>>>(ao, woh, out, nullptr, nullptr);
}

// Round 8
// 216.039 us; speedup vs baseline: 2.5028x; 1.0322x over previous
//
#include <hip/hip_runtime.h>
#include <hip/hip_fp16.h>

#define DM   1024
#define NH   16
#define HD   64
#define BATCH 4
#define SEQ  2048
#define MROWS (BATCH*SEQ)            // 8192
#define BHSD  ((size_t)BATCH*NH*SEQ*HD)  // 8388608 elems

using f32x4 = __attribute__((ext_vector_type(4))) float;
using f16x8 = __attribute__((ext_vector_type(8))) _Float16;
using f16x4 = __attribute__((ext_vector_type(4))) _Float16;
using fp16x2 = __attribute__((ext_vector_type(2))) __fp16;
using u32x2 = __attribute__((ext_vector_type(2))) unsigned int;

__device__ __forceinline__ void gload_lds16(const void* g, void* l) {
    __builtin_amdgcn_global_load_lds(
        (const __attribute__((address_space(1))) void*)g,
        (__attribute__((address_space(3))) void*)l, 16, 0, 0);
}

// ---- VALU-pipe cross-lane reduces via permlane*_swap builtins (no LDS-pipe traffic) ----
__device__ __forceinline__ float red16_max(float v) {
    u32x2 r = __builtin_amdgcn_permlane16_swap(__float_as_uint(v), __float_as_uint(v), false, false);
    return fmaxf(__uint_as_float(r[0]), __uint_as_float(r[1]));   // max(v[i&~16], v[i|16])
}
__device__ __forceinline__ float red32_max(float v) {
    u32x2 r = __builtin_amdgcn_permlane32_swap(__float_as_uint(v), __float_as_uint(v), false, false);
    return fmaxf(__uint_as_float(r[0]), __uint_as_float(r[1]));   // max(v[i&~32], v[i|32])
}
__device__ __forceinline__ float red16_add(float v) {
    u32x2 r = __builtin_amdgcn_permlane16_swap(__float_as_uint(v), __float_as_uint(v), false, false);
    return __uint_as_float(r[0]) + __uint_as_float(r[1]);
}
__device__ __forceinline__ float red32_add(float v) {
    u32x2 r = __builtin_amdgcn_permlane32_swap(__float_as_uint(v), __float_as_uint(v), false, false);
    return __uint_as_float(r[0]) + __uint_as_float(r[1]);
}

// ---------------- fp32 -> fp16 cast ----------------
__global__ __launch_bounds__(256) void f32_to_f16(const float* __restrict__ in,
                                                  _Float16* __restrict__ out, int n) {
    int i = (blockIdx.x * 256 + threadIdx.x) * 4;
    if (i >= n) return;
    float4 v = *(const float4*)(in + i);
    union { _Float16 h[4]; ushort4 u; } cv;
    cv.h[0] = (_Float16)v.x; cv.h[1] = (_Float16)v.y;
    cv.h[2] = (_Float16)v.z; cv.h[3] = (_Float16)v.w;
    *(ushort4*)(out + i) = cv.u;
}

// ---------------- RoPE cos/sin table: [SEQ][32] float2 ----------------
__global__ __launch_bounds__(256) void rope_table(const int* __restrict__ pos,
                                                  float2* __restrict__ tab) {
    int idx = blockIdx.x * 256 + threadIdx.x;    // 65536
    int s = idx >> 5, j = idx & 31;
    float p = (float)pos[s];
    float invf = powf(10000.0f, -(float)j / 32.0f);
    float ang = p * invf;
    tab[idx] = make_float2(cosf(ang), sinf(ang));
}

// ---------------- GEMM: C = A(MxK) * W^T, W row-major (N x K) ----------------
// MODE 0: write fp32 to outF (row-major MxN)
// MODE 1: fused RoPE epilogue -> q,k fp16 in [B][H][S][D]; V TRANSPOSED [B][H][D][S]
//         Q additionally scaled by 0.125*log2(e) so attention can use exp2.
template<int MODE>
__global__ __launch_bounds__(256)
void gemm_f16(const _Float16* __restrict__ A, const _Float16* __restrict__ Bw,
              float* __restrict__ outF, _Float16* __restrict__ qkv,
              const float2* __restrict__ rope) {
    __shared__ __align__(16) _Float16 lds[2][2][128][32];   // [dbuf][A/B][row][k] = 32 KiB
    const int tid  = threadIdx.x;
    const int lane = tid & 63;
    const int wid  = tid >> 6;
    const int m0 = blockIdx.x * 128;
    const int n0 = blockIdx.y * 128;
    const int wm = (wid >> 1) * 64;
    const int wn = (wid & 1) * 64;
    const int g   = lane >> 4;
    const int r16 = lane & 15;

    const int srow0 = (wid*2 + 0)*16 + (lane >> 2);
    const int srow1 = (wid*2 + 1)*16 + (lane >> 2);
    const int sch0 = (lane & 3) ^ ((srow0 >> 1) & 3);
    const int sch1 = (lane & 3) ^ ((srow1 >> 1) & 3);
    const _Float16* Asrc0 = A  + (size_t)(m0 + srow0)*DM + sch0*8;
    const _Float16* Asrc1 = A  + (size_t)(m0 + srow1)*DM + sch1*8;
    const _Float16* Bsrc0 = Bw + (size_t)(n0 + srow0)*DM + sch0*8;
    const _Float16* Bsrc1 = Bw + (size_t)(n0 + srow1)*DM + sch1*8;

    f32x4 acc[4][4] = {};

    #define STAGE(buf, kt) do {                                           \
        const int koff = (kt)*32;                                         \
        _Float16* bA = &lds[(buf)][0][0][0];                              \
        _Float16* bB = &lds[(buf)][1][0][0];                              \
        gload_lds16(Asrc0 + koff, bA + (wid*2 + 0)*512);                  \
        gload_lds16(Asrc1 + koff, bA + (wid*2 + 1)*512);                  \
        gload_lds16(Bsrc0 + koff, bB + (wid*2 + 0)*512);                  \
        gload_lds16(Bsrc1 + koff, bB + (wid*2 + 1)*512);                  \
    } while (0)

    STAGE(0, 0);
    for (int kt = 0; kt < 32; ++kt) {
        __syncthreads();
        if (kt + 1 < 32) STAGE((kt + 1) & 1, kt + 1);
        const int buf = kt & 1;
        f16x8 af[4], bf[4];
        #pragma unroll
        for (int i = 0; i < 4; ++i) {
            int rowa = wm + i*16 + r16;
            af[i] = *(const f16x8*)&lds[buf][0][rowa][(g ^ ((rowa >> 1) & 3)) * 8];
            int rowb = wn + i*16 + r16;
            bf[i] = *(const f16x8*)&lds[buf][1][rowb][(g ^ ((rowb >> 1) & 3)) * 8];
        }
        #pragma unroll
        for (int i = 0; i < 4; ++i)
            #pragma unroll
            for (int j = 0; j < 4; ++j)
                acc[i][j] = __builtin_amdgcn_mfma_f32_16x16x32_f16(af[i], bf[j], acc[i][j], 0, 0, 0);
    }
    #undef STAGE

    // epilogue
    #pragma unroll
    for (int i = 0; i < 4; ++i) {
        #pragma unroll
        for (int j = 0; j < 4; ++j) {
            if constexpr (MODE == 0) {
                #pragma unroll
                for (int r = 0; r < 4; ++r) {
                    const int m = m0 + wm + i*16 + g*4 + r;
                    const int n = n0 + wn + j*16 + r16;
                    outF[(size_t)m*DM + n] = acc[i][j][r];
                }
            } else {
                const int n = n0 + wn + j*16 + r16;
                const int sel = n >> 10;              // 0=q 1=k 2=v (block-uniform)
                const int cc = n & 1023;
                const int h = cc >> 6, dd = cc & 63;
                if (sel == 2) {
                    // V^T: 4 consecutive s (r=0..3) at fixed d -> one 8B store
                    const int mb = m0 + wm + i*16 + g*4;
                    const int s0 = mb & (SEQ - 1), b = mb >> 11;
                    f16x4 pk;
                    #pragma unroll
                    for (int r = 0; r < 4; ++r) pk[r] = (_Float16)acc[i][j][r];
                    *(f16x4*)(qkv + 2*BHSD + ((size_t)((b*NH + h)*HD + dd))*SEQ + s0) = pk;
                } else {
                    #pragma unroll
                    for (int r = 0; r < 4; ++r) {
                        const int m = m0 + wm + i*16 + g*4 + r;
                        float v = acc[i][j][r];
                        float vp = __shfl_xor(v, 1);          // partner column (n^1)
                        const int s = m & (SEQ - 1), b = m >> 11;
                        float2 cs = rope[(s << 5) + (dd >> 1)];
                        float o;
                        if (dd & 1) o = vp * cs.y + v * cs.x;   // x1*sin + x2*cos
                        else        o = v * cs.x - vp * cs.y;   // x1*cos - x2*sin
                        if (sel == 0) o *= 0.18033688f;         // 1/sqrt(HD) * log2(e)
                        qkv[(size_t)sel*BHSD + ((size_t)((b*NH + h)*SEQ + s))*HD + dd] = (_Float16)o;
                    }
                }
            }
        }
    }
}

// ---------------- per-KV-tile attention step (swapped QK^T, in-register softmax) ----------
// Scores in log2 domain (Q pre-scaled by 0.125*log2e); exp2 everywhere.
// Wave owns 16 q rows (q = Rq + r16). KV tile = 64.
// Cross-lane traffic (P redistribution + reduces) is all VALU permlane swaps; the
// only LDS-pipe ops are the 16 ds_read_b128 K/V fragment loads.
__device__ __forceinline__ void process_tile(
    const _Float16 (*__restrict__ Klb)[64], const _Float16 (*__restrict__ Vlb)[64],
    const f16x8 (&qf)[2], f32x4 (&ot)[4], float &m, float &l,
    const int Rq, const int kv0, const int g, const int r16) {

    // ---- S^T = K Q^T : sT[n][r] = S[q = Rq+r16][kv = kv0+n*16+4g+r]
    f32x4 sT[4] = {};
    const int kchunkBase = r16 & 7;
    __builtin_amdgcn_s_setprio(1);
    #pragma unroll
    for (int ks = 0; ks < 2; ++ks) {
        #pragma unroll
        for (int n = 0; n < 4; ++n) {
            f16x8 kf = *(const f16x8*)&Klb[n*16 + r16][(((ks<<2)|g) ^ kchunkBase)*8];
            sT[n] = __builtin_amdgcn_mfma_f32_16x16x32_f16(kf, qf[ks], sT[n], 0, 0, 0);
        }
    }
    __builtin_amdgcn_s_setprio(0);

    // ---- online softmax (log2 domain) ----
    const bool full = (kv0 + 63 <= Rq);          // wave-uniform
    float sv[16];
    if (full) {
        #pragma unroll
        for (int n = 0; n < 4; ++n)
            #pragma unroll
            for (int r = 0; r < 4; ++r) sv[n*4 + r] = sT[n][r];
    } else {
        const int q = Rq + r16;
        #pragma unroll
        for (int n = 0; n < 4; ++n)
            #pragma unroll
            for (int r = 0; r < 4; ++r)
                sv[n*4 + r] = (kv0 + n*16 + 4*g + r <= q) ? sT[n][r] : -INFINITY;
    }
    float mx = sv[0];
    #pragma unroll
    for (int i = 1; i < 16; ++i) mx = fmaxf(mx, sv[i]);
    mx = red32_max(red16_max(mx));
    // defer-max (T13): rescale only when max grew by > 8 (log2 units -> P <= 256)
    const bool need = (mx > m + 8.f);
    if (__any(need)) {
        float mnew = need ? mx : m;
        float al = exp2f(m - mnew);
        m = mnew;
        l *= al;
        #pragma unroll
        for (int n = 0; n < 4; ++n) ot[n] *= al;
    }
    float ps = 0.f;
    #pragma unroll
    for (int i = 0; i < 16; ++i) { sv[i] = exp2f(sv[i] - m); ps += sv[i]; }
    l += red32_add(red16_add(ps));

    // ---- pack P to fp16 pairs: pk[t][rp] = P[kv = 16t + 4g + 2rp (+1)] at this lane ----
    uint pk[4][2];
    #pragma unroll
    for (int t = 0; t < 4; ++t)
        #pragma unroll
        for (int rp = 0; rp < 2; ++rp) {
            union { fp16x2 h; uint u; } cv;
            cv.h = __builtin_amdgcn_cvt_pkrtz(sv[t*4 + 2*rp], sv[t*4 + 2*rp + 1]);
            pk[t][rp] = cv.u;
        }
    // ---- permlane swaps -> standard B-frag words w[ks][j2] (k'' = 32ks + 8g + 2j2) ----
    // swap32(pk[2k][rp], pk[2k+1][rp]) then swap16 of the pair:
    //   result[0] = w[k][rp]   (lane g holds kv = 32k + 8g + 2rp   from group 2(g&1))
    //   result[1] = w[k][2+rp] (lane g holds kv = 32k + 8g + 4+2rp from group 2(g&1)+1)
    uint w[2][4];
    #pragma unroll
    for (int kk = 0; kk < 2; ++kk)
        #pragma unroll
        for (int rp = 0; rp < 2; ++rp) {
            u32x2 s32 = __builtin_amdgcn_permlane32_swap(pk[2*kk][rp], pk[2*kk + 1][rp], false, false);
            u32x2 s16 = __builtin_amdgcn_permlane16_swap(s32[0], s32[1], false, false);
            w[kk][rp]     = s16[0];
            w[kk][2 + rp] = s16[1];
        }

    // ---- O^T += V^T P^T ----
    __builtin_amdgcn_s_setprio(1);
    #pragma unroll
    for (int ks = 0; ks < 2; ++ks) {
        union { uint u[4]; f16x8 h; } pb;
        #pragma unroll
        for (int j2 = 0; j2 < 4; ++j2) pb.u[j2] = w[ks][j2];
        #pragma unroll
        for (int n = 0; n < 4; ++n) {
            f16x8 vf = *(const f16x8*)&Vlb[n*16 + r16][(((ks<<2)|g) ^ kchunkBase)*8];
            ot[n] = __builtin_amdgcn_mfma_f32_16x16x32_f16(vf, pb.h, ot[n], 0, 0, 0);
        }
    }
    __builtin_amdgcn_s_setprio(0);
}

// ---------------- flash attention: diagonal-paired 64-row q-tiles, 16 q/wave ----------------
// Block (bh, j): q-tile hi = 31-j AND q-tile lo = j (uniform ~33 tile-computes).
// 1024 blocks -> 4 blocks/CU -> 4 waves/SIMD for latency hiding.
__global__ __launch_bounds__(256, 4)
void attn_kernel(const _Float16* __restrict__ qkv, _Float16* __restrict__ ao) {
    const int tid = threadIdx.x, lane = tid & 63, w = tid >> 6;
    const int g = lane >> 4, r16 = lane & 15;
    const int bh = blockIdx.x;                       // id%8 == bh%8 -> same bh, same XCD
    const int jq = blockIdx.y;                       // 0..15
    const int q0h = (31 - jq) * 64, q0l = jq * 64;
    const _Float16* Q   = qkv + (size_t)bh * SEQ * HD;
    const _Float16* Kp  = qkv + BHSD + (size_t)bh * SEQ * HD;
    const _Float16* Vpt = qkv + 2*BHSD + (size_t)bh * SEQ * HD;   // [d][s]

    __shared__ __align__(16) _Float16 Kl[2][64][64];   // 16 KB
    __shared__ __align__(16) _Float16 Vl[2][64][64];   // 16 KB

    // staging addresses (unit u = shot*256 + tid; row = u>>3, phys chunk = u&7)
    const int rA = tid >> 3,        rB = 32 + (tid >> 3);
    const int lcA = (tid & 7) ^ (rA & 7), lcB = (tid & 7) ^ (rB & 7);
    const _Float16* KsrcA = Kp  + (size_t)rA*HD + lcA*8;
    const _Float16* KsrcB = Kp  + (size_t)rB*HD + lcB*8;
    const _Float16* VsrcA = Vpt + (size_t)rA*SEQ + lcA*8;
    const _Float16* VsrcB = Vpt + (size_t)rB*SEQ + lcB*8;

    const int Rh = q0h + w*16, Rl = q0l + w*16;
    f16x8 qfh[2], qfl[2];
    #pragma unroll
    for (int ks = 0; ks < 2; ++ks) {
        qfh[ks] = *(const f16x8*)(Q + (size_t)(Rh + r16)*HD + ks*32 + g*8);
        qfl[ks] = *(const f16x8*)(Q + (size_t)(Rl + r16)*HD + ks*32 + g*8);
    }

    f32x4 oth[4] = {}, otl[4] = {};
    float mh = -INFINITY, lh = 0.f, ml_ = -INFINITY, ll_ = 0.f;

    const int nth = (q0h >> 6) + 1;                  // staged tiles (covers hi q-tile)
    const int ntl = (q0l >> 6) + 1;                  // lo-compute tiles

    #define STAGE(buf, kv0) do {                                              \
        gload_lds16(KsrcA + (size_t)(kv0)*HD, &Kl[(buf)][0][0] + tid*8);      \
        gload_lds16(KsrcB + (size_t)(kv0)*HD, &Kl[(buf)][0][0] + (256+tid)*8);\
        gload_lds16(VsrcA + (kv0),            &Vl[(buf)][0][0] + tid*8);      \
        gload_lds16(VsrcB + (kv0),            &Vl[(buf)][0][0] + (256+tid)*8);\
    } while (0)

    STAGE(0, 0);
    for (int kt = 0; kt < nth; ++kt) {
        const int kv0 = kt << 6;
        __syncthreads();                             // buf[kt&1] ready; other buf free
        if (kt + 1 < nth) STAGE((kt + 1) & 1, (kt + 1) << 6);
        const int buf = kt & 1;

        if (kv0 <= Rh + 15)
            process_tile(Kl[buf], Vl[buf], qfh, oth, mh, lh, Rh, kv0, g, r16);
        if (kt < ntl)
            process_tile(Kl[buf], Vl[buf], qfl, otl, ml_, ll_, Rl, kv0, g, r16);
    }
    #undef STAGE

    // normalize + store both q-tiles: lane writes d = n*16+g*4 .. +3 for its q row
    const int b = bh >> 4, h = bh & 15;
    const float invh = 1.0f / lh, invl = 1.0f / ll_;
    _Float16* dsth = ao + ((size_t)(b*SEQ + Rh + r16))*DM + h*HD + g*4;
    _Float16* dstl = ao + ((size_t)(b*SEQ + Rl + r16))*DM + h*HD + g*4;
    #pragma unroll
    for (int n = 0; n < 4; ++n) {
        f16x4 pkh, pkl;
        #pragma unroll
        for (int r = 0; r < 4; ++r) {
            pkh[r] = (_Float16)(oth[n][r] * invh);
            pkl[r] = (_Float16)(otl[n][r] * invl);
        }
        *(f16x4*)(dsth + n*16) = pkh;
        *(f16x4*)(dstl + n*16) = pkl;
    }
}

// ---------------- launcher ----------------
extern "C" void kernel_launch(void* const* d_in, const int* in_sizes, int n_in,
                              void* d_out, int out_size, void* d_ws, size_t ws_size,
                              hipStream_t stream) {
    const float* x  = (const float*)d_in[0];
    const int*   tp = (const int*)d_in[1];
    const float* wq = (const float*)d_in[2];
    const float* wk = (const float*)d_in[3];
    const float* wv = (const float*)d_in[4];
    const float* wo = (const float*)d_in[5];
    float* out = (float*)d_out;

    char* ws = (char*)d_ws;
    _Float16* xh  = (_Float16*)(ws);                         // 16,777,216 B
    _Float16* whq = (_Float16*)(ws + 16777216);              //  6,291,456 B (wq|wk|wv)
    _Float16* woh = (_Float16*)(ws + 23068672);              //  2,097,152 B
    _Float16* qkv = (_Float16*)(ws + 25165824);              // 50,331,648 B
    _Float16* ao  = (_Float16*)(ws + 75497472);              // 16,777,216 B
    float2*   rope= (float2*)  (ws + 92274688);              //    524,288 B  (total ~92.8 MB)

    f32_to_f16<<<MROWS*DM/1024, 256, 0, stream>>>(x, xh, MROWS*DM);
    f32_to_f16<<<DM*DM/1024, 256, 0, stream>>>(wq, whq,            DM*DM);
    f32_to_f16<<<DM*DM/1024, 256, 0, stream>>>(wk, whq + DM*DM,    DM*DM);
    f32_to_f16<<<DM*DM/1024, 256, 0, stream>>>(wv, whq + 2*DM*DM,  DM*DM);
    f32_to_f16<<<DM*DM/1024, 256, 0, stream>>>(wo, woh,            DM*DM);
    rope_table<<<SEQ*32/256, 256, 0, stream>>>(tp, rope);

    gemm_f16<1><<<dim3(MROWS/128, 3*DM/128), 256, 0, stream>>>(xh, whq, nullptr, qkv, rope);
    attn_kernel<<<dim3(BATCH*NH, 16), 256, 0, stream>>>(qkv, ao);
    gemm_f16<0><<<dim3(MROWS/128, DM/128), 256, 0, stream>>>(ao, woh, out, nullptr, nullptr);
}

// Round 9
// 207.331 us; speedup vs baseline: 2.6079x; 1.0420x over previous
//
#include <hip/hip_runtime.h>
#include <hip/hip_fp16.h>

#define DM   1024
#define NH   16
#define HD   64
#define BATCH 4
#define SEQ  2048
#define MROWS (BATCH*SEQ)            // 8192
#define BHSD  ((size_t)BATCH*NH*SEQ*HD)  // 8388608 elems

using f32x4 = __attribute__((ext_vector_type(4))) float;
using f16x8 = __attribute__((ext_vector_type(8))) _Float16;
using f16x4 = __attribute__((ext_vector_type(4))) _Float16;
using fp16x2 = __attribute__((ext_vector_type(2))) __fp16;
using u32x2 = __attribute__((ext_vector_type(2))) unsigned int;

__device__ __forceinline__ void gload_lds16(const void* g, void* l) {
    __builtin_amdgcn_global_load_lds(
        (const __attribute__((address_space(1))) void*)g,
        (__attribute__((address_space(3))) void*)l, 16, 0, 0);
}

// ---- VALU-pipe cross-lane reduces via permlane*_swap builtins (no LDS-pipe traffic) ----
__device__ __forceinline__ float red16_max(float v) {
    u32x2 r = __builtin_amdgcn_permlane16_swap(__float_as_uint(v), __float_as_uint(v), false, false);
    return fmaxf(__uint_as_float(r[0]), __uint_as_float(r[1]));
}
__device__ __forceinline__ float red32_max(float v) {
    u32x2 r = __builtin_amdgcn_permlane32_swap(__float_as_uint(v), __float_as_uint(v), false, false);
    return fmaxf(__uint_as_float(r[0]), __uint_as_float(r[1]));
}
__device__ __forceinline__ float red16_add(float v) {
    u32x2 r = __builtin_amdgcn_permlane16_swap(__float_as_uint(v), __float_as_uint(v), false, false);
    return __uint_as_float(r[0]) + __uint_as_float(r[1]);
}
__device__ __forceinline__ float red32_add(float v) {
    u32x2 r = __builtin_amdgcn_permlane32_swap(__float_as_uint(v), __float_as_uint(v), false, false);
    return __uint_as_float(r[0]) + __uint_as_float(r[1]);
}

// ---------------- fp32 -> fp16 cast ----------------
__global__ __launch_bounds__(256) void f32_to_f16(const float* __restrict__ in,
                                                  _Float16* __restrict__ out, int n) {
    int i = (blockIdx.x * 256 + threadIdx.x) * 4;
    if (i >= n) return;
    float4 v = *(const float4*)(in + i);
    union { _Float16 h[4]; ushort4 u; } cv;
    cv.h[0] = (_Float16)v.x; cv.h[1] = (_Float16)v.y;
    cv.h[2] = (_Float16)v.z; cv.h[3] = (_Float16)v.w;
    *(ushort4*)(out + i) = cv.u;
}

// ---------------- RoPE cos/sin table: [SEQ][32] float2 ----------------
__global__ __launch_bounds__(256) void rope_table(const int* __restrict__ pos,
                                                  float2* __restrict__ tab) {
    int idx = blockIdx.x * 256 + threadIdx.x;    // 65536
    int s = idx >> 5, j = idx & 31;
    float p = (float)pos[s];
    float invf = powf(10000.0f, -(float)j / 32.0f);
    float ang = p * invf;
    tab[idx] = make_float2(cosf(ang), sinf(ang));
}

// ---------------- 8-wave phase-pipelined GEMM: C = A(MxK) * W^T ----------------
// BM=256, BN=128, BK=64, K=1024 (NK=16 tiles), 512 threads (8 waves, 4M x 2N).
// Counted-vmcnt pipeline (T3+T4): 2-deep prefetch, vmcnt(6) per K-tile, never 0
// in steady state. LDS XOR-swizzled (T2), setprio around MFMA (T5).
// MODE 0: fp32 out.  MODE 1: RoPE epilogue -> q,k [B][H][S][D], V^T [B][H][D][S].
template<int MODE>
__global__ __launch_bounds__(512, 2)
void gemm8p(const _Float16* __restrict__ A, const _Float16* __restrict__ Bw,
            float* __restrict__ outF, _Float16* __restrict__ qkv,
            const float2* __restrict__ rope) {
    constexpr int NK = DM / 64;                    // 16 K-tiles
    __shared__ __align__(16) _Float16 ldsA[2][256][64];   // 64 KB
    __shared__ __align__(16) _Float16 ldsB[2][128][64];   // 32 KB
    const int tid  = threadIdx.x;
    const int lane = tid & 63;
    const int wid  = tid >> 6;                     // 0..7
    const int m0 = blockIdx.x * 256;
    const int n0 = blockIdx.y * 128;
    const int wm = (wid >> 1) * 64;                // 4 wave-rows
    const int wn = (wid & 1) * 64;                 // 2 wave-cols
    const int g   = lane >> 4;
    const int r16 = lane & 15;
    const int cx  = r16 & 7;                       // read-side XOR key

    // staging: tile unit u -> row = u>>3, phys chunk = u&7 holds logical chunk
    // (u&7)^(row&7); source pre-swizzled so LDS dest stays linear.
    const _Float16* srcA[4];
    int dstA[4];
    #pragma unroll
    for (int L = 0; L < 4; ++L) {
        const int u = L*512 + tid, row = u >> 3, c = (u & 7) ^ (row & 7);
        srcA[L] = A + (size_t)(m0 + row)*DM + c*8;
        dstA[L] = u*8;
    }
    const _Float16* srcB[2];
    int dstB[2];
    #pragma unroll
    for (int L = 0; L < 2; ++L) {
        const int u = L*512 + tid, row = u >> 3, c = (u & 7) ^ (row & 7);
        srcB[L] = Bw + (size_t)(n0 + row)*DM + c*8;
        dstB[L] = u*8;
    }
    _Float16* lAf = &ldsA[0][0][0];
    _Float16* lBf = &ldsB[0][0][0];

    #define STAGE(cur, kt) do {                                        \
        const int ko = (kt)*64;                                        \
        gload_lds16(srcA[0] + ko, lAf + (cur)*16384 + dstA[0]);        \
        gload_lds16(srcA[1] + ko, lAf + (cur)*16384 + dstA[1]);        \
        gload_lds16(srcA[2] + ko, lAf + (cur)*16384 + dstA[2]);        \
        gload_lds16(srcA[3] + ko, lAf + (cur)*16384 + dstA[3]);        \
        gload_lds16(srcB[0] + ko, lBf + (cur)*8192 + dstB[0]);         \
        gload_lds16(srcB[1] + ko, lBf + (cur)*8192 + dstB[1]);         \
    } while (0)

    f32x4 acc[4][4] = {};

    STAGE(0, 0);
    STAGE(1, 1);
    asm volatile("s_waitcnt vmcnt(6)" ::: "memory");   // tile 0 landed; tile 1 in flight
    __builtin_amdgcn_s_barrier();

    for (int t = 0; t < NK; ++t) {
        const int cur = t & 1;
        const _Float16* lA = lAf + cur*16384;
        const _Float16* lB = lBf + cur*8192;

        // ---- phase A: ks = 0 ----
        f16x8 a0[4], b0[4];
        #pragma unroll
        for (int i = 0; i < 4; ++i)
            a0[i] = *(const f16x8*)(lA + (wm + i*16 + r16)*64 + ((g ^ cx) * 8));
        #pragma unroll
        for (int j = 0; j < 4; ++j)
            b0[j] = *(const f16x8*)(lB + (wn + j*16 + r16)*64 + ((g ^ cx) * 8));
        asm volatile("s_waitcnt lgkmcnt(0)" ::: "memory");
        __builtin_amdgcn_sched_barrier(0);
        __builtin_amdgcn_s_barrier();
        __builtin_amdgcn_s_setprio(1);
        #pragma unroll
        for (int i = 0; i < 4; ++i)
            #pragma unroll
            for (int j = 0; j < 4; ++j)
                acc[i][j] = __builtin_amdgcn_mfma_f32_16x16x32_f16(a0[i], b0[j], acc[i][j], 0, 0, 0);
        __builtin_amdgcn_s_setprio(0);
        __builtin_amdgcn_s_barrier();

        // ---- phase B: ks = 1 ----
        f16x8 a1[4], b1[4];
        #pragma unroll
        for (int i = 0; i < 4; ++i)
            a1[i] = *(const f16x8*)(lA + (wm + i*16 + r16)*64 + (((4|g) ^ cx) * 8));
        #pragma unroll
        for (int j = 0; j < 4; ++j)
            b1[j] = *(const f16x8*)(lB + (wn + j*16 + r16)*64 + (((4|g) ^ cx) * 8));
        asm volatile("s_waitcnt lgkmcnt(0)" ::: "memory");   // my reads of buf[cur] done
        __builtin_amdgcn_sched_barrier(0);
        __builtin_amdgcn_s_barrier();                        // ALL waves done with buf[cur]
        if (t + 2 < NK) STAGE(cur, t + 2);                   // overwrite cur with t+2
        __builtin_amdgcn_s_setprio(1);
        #pragma unroll
        for (int i = 0; i < 4; ++i)
            #pragma unroll
            for (int j = 0; j < 4; ++j)
                acc[i][j] = __builtin_amdgcn_mfma_f32_16x16x32_f16(a1[i], b1[j], acc[i][j], 0, 0, 0);
        __builtin_amdgcn_s_setprio(0);
        if (t + 2 < NK)      asm volatile("s_waitcnt vmcnt(6)" ::: "memory");  // t+1 ready
        else if (t == NK-2)  asm volatile("s_waitcnt vmcnt(0)" ::: "memory");  // drain tail
        __builtin_amdgcn_sched_barrier(0);
        __builtin_amdgcn_s_barrier();
    }
    #undef STAGE

    // ---- epilogue ----
    #pragma unroll
    for (int i = 0; i < 4; ++i) {
        #pragma unroll
        for (int j = 0; j < 4; ++j) {
            if constexpr (MODE == 0) {
                #pragma unroll
                for (int r = 0; r < 4; ++r) {
                    const int m = m0 + wm + i*16 + g*4 + r;
                    const int n = n0 + wn + j*16 + r16;
                    outF[(size_t)m*DM + n] = acc[i][j][r];
                }
            } else {
                const int n = n0 + wn + j*16 + r16;
                const int sel = n >> 10;              // 0=q 1=k 2=v (block-uniform)
                const int cc = n & 1023;
                const int h = cc >> 6, dd = cc & 63;
                if (sel == 2) {
                    const int mb = m0 + wm + i*16 + g*4;
                    const int s0 = mb & (SEQ - 1), b = mb >> 11;
                    f16x4 pk;
                    #pragma unroll
                    for (int r = 0; r < 4; ++r) pk[r] = (_Float16)acc[i][j][r];
                    *(f16x4*)(qkv + 2*BHSD + ((size_t)((b*NH + h)*HD + dd))*SEQ + s0) = pk;
                } else {
                    #pragma unroll
                    for (int r = 0; r < 4; ++r) {
                        const int m = m0 + wm + i*16 + g*4 + r;
                        float v = acc[i][j][r];
                        float vp = __shfl_xor(v, 1);          // partner column (n^1)
                        const int s = m & (SEQ - 1), b = m >> 11;
                        float2 cs = rope[(s << 5) + (dd >> 1)];
                        float o;
                        if (dd & 1) o = vp * cs.y + v * cs.x;   // x1*sin + x2*cos
                        else        o = v * cs.x - vp * cs.y;   // x1*cos - x2*sin
                        if (sel == 0) o *= 0.18033688f;         // 1/sqrt(HD) * log2(e)
                        qkv[(size_t)sel*BHSD + ((size_t)((b*NH + h)*SEQ + s))*HD + dd] = (_Float16)o;
                    }
                }
            }
        }
    }
}

// ---------------- per-KV-tile attention step (swapped QK^T, in-register softmax) ----------
__device__ __forceinline__ void process_tile(
    const _Float16 (*__restrict__ Klb)[64], const _Float16 (*__restrict__ Vlb)[64],
    const f16x8 (&qf)[2], f32x4 (&ot)[4], float &m, float &l,
    const int Rq, const int kv0, const int g, const int r16) {

    f32x4 sT[4] = {};
    const int kchunkBase = r16 & 7;
    __builtin_amdgcn_s_setprio(1);
    #pragma unroll
    for (int ks = 0; ks < 2; ++ks) {
        #pragma unroll
        for (int n = 0; n < 4; ++n) {
            f16x8 kf = *(const f16x8*)&Klb[n*16 + r16][(((ks<<2)|g) ^ kchunkBase)*8];
            sT[n] = __builtin_amdgcn_mfma_f32_16x16x32_f16(kf, qf[ks], sT[n], 0, 0, 0);
        }
    }
    __builtin_amdgcn_s_setprio(0);

    const bool full = (kv0 + 63 <= Rq);
    float sv[16];
    if (full) {
        #pragma unroll
        for (int n = 0; n < 4; ++n)
            #pragma unroll
            for (int r = 0; r < 4; ++r) sv[n*4 + r] = sT[n][r];
    } else {
        const int q = Rq + r16;
        #pragma unroll
        for (int n = 0; n < 4; ++n)
            #pragma unroll
            for (int r = 0; r < 4; ++r)
                sv[n*4 + r] = (kv0 + n*16 + 4*g + r <= q) ? sT[n][r] : -INFINITY;
    }
    float mx = sv[0];
    #pragma unroll
    for (int i = 1; i < 16; ++i) mx = fmaxf(mx, sv[i]);
    mx = red32_max(red16_max(mx));
    const bool need = (mx > m + 8.f);
    if (__any(need)) {
        float mnew = need ? mx : m;
        float al = exp2f(m - mnew);
        m = mnew;
        l *= al;
        #pragma unroll
        for (int n = 0; n < 4; ++n) ot[n] *= al;
    }
    float ps = 0.f;
    #pragma unroll
    for (int i = 0; i < 16; ++i) { sv[i] = exp2f(sv[i] - m); ps += sv[i]; }
    l += red32_add(red16_add(ps));

    uint pk[4][2];
    #pragma unroll
    for (int t = 0; t < 4; ++t)
        #pragma unroll
        for (int rp = 0; rp < 2; ++rp) {
            union { fp16x2 h; uint u; } cv;
            cv.h = __builtin_amdgcn_cvt_pkrtz(sv[t*4 + 2*rp], sv[t*4 + 2*rp + 1]);
            pk[t][rp] = cv.u;
        }
    uint w[2][4];
    #pragma unroll
    for (int kk = 0; kk < 2; ++kk)
        #pragma unroll
        for (int rp = 0; rp < 2; ++rp) {
            u32x2 s32 = __builtin_amdgcn_permlane32_swap(pk[2*kk][rp], pk[2*kk + 1][rp], false, false);
            u32x2 s16 = __builtin_amdgcn_permlane16_swap(s32[0], s32[1], false, false);
            w[kk][rp]     = s16[0];
            w[kk][2 + rp] = s16[1];
        }

    __builtin_amdgcn_s_setprio(1);
    #pragma unroll
    for (int ks = 0; ks < 2; ++ks) {
        union { uint u[4]; f16x8 h; } pb;
        #pragma unroll
        for (int j2 = 0; j2 < 4; ++j2) pb.u[j2] = w[ks][j2];
        #pragma unroll
        for (int n = 0; n < 4; ++n) {
            f16x8 vf = *(const f16x8*)&Vlb[n*16 + r16][(((ks<<2)|g) ^ kchunkBase)*8];
            ot[n] = __builtin_amdgcn_mfma_f32_16x16x32_f16(vf, pb.h, ot[n], 0, 0, 0);
        }
    }
    __builtin_amdgcn_s_setprio(0);
}

// ---------------- flash attention: diagonal-paired 64-row q-tiles, 16 q/wave ----------------
__global__ __launch_bounds__(256, 4)
void attn_kernel(const _Float16* __restrict__ qkv, _Float16* __restrict__ ao) {
    const int tid = threadIdx.x, lane = tid & 63, w = tid >> 6;
    const int g = lane >> 4, r16 = lane & 15;
    const int bh = blockIdx.x;
    const int jq = blockIdx.y;                       // 0..15
    const int q0h = (31 - jq) * 64, q0l = jq * 64;
    const _Float16* Q   = qkv + (size_t)bh * SEQ * HD;
    const _Float16* Kp  = qkv + BHSD + (size_t)bh * SEQ * HD;
    const _Float16* Vpt = qkv + 2*BHSD + (size_t)bh * SEQ * HD;   // [d][s]

    __shared__ __align__(16) _Float16 Kl[2][64][64];
    __shared__ __align__(16) _Float16 Vl[2][64][64];

    const int rA = tid >> 3,        rB = 32 + (tid >> 3);
    const int lcA = (tid & 7) ^ (rA & 7), lcB = (tid & 7) ^ (rB & 7);
    const _Float16* KsrcA = Kp  + (size_t)rA*HD + lcA*8;
    const _Float16* KsrcB = Kp  + (size_t)rB*HD + lcB*8;
    const _Float16* VsrcA = Vpt + (size_t)rA*SEQ + lcA*8;
    const _Float16* VsrcB = Vpt + (size_t)rB*SEQ + lcB*8;

    const int Rh = q0h + w*16, Rl = q0l + w*16;
    f16x8 qfh[2], qfl[2];
    #pragma unroll
    for (int ks = 0; ks < 2; ++ks) {
        qfh[ks] = *(const f16x8*)(Q + (size_t)(Rh + r16)*HD + ks*32 + g*8);
        qfl[ks] = *(const f16x8*)(Q + (size_t)(Rl + r16)*HD + ks*32 + g*8);
    }

    f32x4 oth[4] = {}, otl[4] = {};
    float mh = -INFINITY, lh = 0.f, ml_ = -INFINITY, ll_ = 0.f;

    const int nth = (q0h >> 6) + 1;
    const int ntl = (q0l >> 6) + 1;

    #define STAGE(buf, kv0) do {                                              \
        gload_lds16(KsrcA + (size_t)(kv0)*HD, &Kl[(buf)][0][0] + tid*8);      \
        gload_lds16(KsrcB + (size_t)(kv0)*HD, &Kl[(buf)][0][0] + (256+tid)*8);\
        gload_lds16(VsrcA + (kv0),            &Vl[(buf)][0][0] + tid*8);      \
        gload_lds16(VsrcB + (kv0),            &Vl[(buf)][0][0] + (256+tid)*8);\
    } while (0)

    STAGE(0, 0);
    for (int kt = 0; kt < nth; ++kt) {
        const int kv0 = kt << 6;
        __syncthreads();
        if (kt + 1 < nth) STAGE((kt + 1) & 1, (kt + 1) << 6);
        const int buf = kt & 1;

        if (kv0 <= Rh + 15)
            process_tile(Kl[buf], Vl[buf], qfh, oth, mh, lh, Rh, kv0, g, r16);
        if (kt < ntl)
            process_tile(Kl[buf], Vl[buf], qfl, otl, ml_, ll_, Rl, kv0, g, r16);
    }
    #undef STAGE

    const int b = bh >> 4, h = bh & 15;
    const float invh = 1.0f / lh, invl = 1.0f / ll_;
    _Float16* dsth = ao + ((size_t)(b*SEQ + Rh + r16))*DM + h*HD + g*4;
    _Float16* dstl = ao + ((size_t)(b*SEQ + Rl + r16))*DM + h*HD + g*4;
    #pragma unroll
    for (int n = 0; n < 4; ++n) {
        f16x4 pkh, pkl;
        #pragma unroll
        for (int r = 0; r < 4; ++r) {
            pkh[r] = (_Float16)(oth[n][r] * invh);
            pkl[r] = (_Float16)(otl[n][r] * invl);
        }
        *(f16x4*)(dsth + n*16) = pkh;
        *(f16x4*)(dstl + n*16) = pkl;
    }
}

// ---------------- launcher ----------------
extern "C" void kernel_launch(void* const* d_in, const int* in_sizes, int n_in,
                              void* d_out, int out_size, void* d_ws, size_t ws_size,
                              hipStream_t stream) {
    const float* x  = (const float*)d_in[0];
    const int*   tp = (const int*)d_in[1];
    const float* wq = (const float*)d_in[2];
    const float* wk = (const float*)d_in[3];
    const float* wv = (const float*)d_in[4];
    const float* wo = (const float*)d_in[5];
    float* out = (float*)d_out;

    char* ws = (char*)d_ws;
    _Float16* xh  = (_Float16*)(ws);                         // 16,777,216 B
    _Float16* whq = (_Float16*)(ws + 16777216);              //  6,291,456 B (wq|wk|wv)
    _Float16* woh = (_Float16*)(ws + 23068672);              //  2,097,152 B
    _Float16* qkv = (_Float16*)(ws + 25165824);              // 50,331,648 B
    _Float16* ao  = (_Float16*)(ws + 75497472);              // 16,777,216 B
    float2*   rope= (float2*)  (ws + 92274688);              //    524,288 B  (total ~92.8 MB)

    f32_to_f16<<<MROWS*DM/1024, 256, 0, stream>>>(x, xh, MROWS*DM);
    f32_to_f16<<<DM*DM/1024, 256, 0, stream>>>(wq, whq,            DM*DM);
    f32_to_f16<<<DM*DM/1024, 256, 0, stream>>>(wk, whq + DM*DM,    DM*DM);
    f32_to_f16<<<DM*DM/1024, 256, 0, stream>>>(wv, whq + 2*DM*DM,  DM*DM);
    f32_to_f16<<<DM*DM/1024, 256, 0, stream>>>(wo, woh,            DM*DM);
    rope_table<<<SEQ*32/256, 256, 0, stream>>>(tp, rope);

    gemm8p<1><<<dim3(MROWS/256, 3*DM/128), 512, 0, stream>>>(xh, whq, nullptr, qkv, rope);
    attn_kernel<<<dim3(BATCH*NH, 16), 256, 0, stream>>>(qkv, ao);
    gemm8p<0><<<dim3(MROWS/256, DM/128), 512, 0, stream>>>(ao, woh, out, nullptr, nullptr);
}